// Round 7
// baseline (1315.481 us; speedup 1.0000x reference)
//
#include <hip/hip_runtime.h>
#include <hip/hip_bf16.h>

// GroupedMLP: E=8, T=1024, H=2048, I=5632
// Round 7: occupancy fix. 256x128 tile, BK=32, 48KB LDS dbuf, 8 waves each
// computing 64x64 (acc=64 VGPR) -> VGPR<=128 & 2 blocks/CU (4 waves/SIMD,
// two independent barrier domains per CU). r6 streaming inner loop kept:
// hold 4 B-frags, ping-pong A-frags, 2 barriers + counted vmcnt(3) per tile.
// Swizzle for 64B rows: k-slot bits 3-4 XOR (row>>2)&3, baked into ws
// layouts (gload_lds stays linear), applied on ds_read.

#define EXPERTS 8
#define TOK     1024
#define HID     2048
#define INTER   5632
#define I2      (2 * INTER)

typedef __bf16 bf16x8 __attribute__((ext_vector_type(8)));
typedef float  f32x4  __attribute__((ext_vector_type(4)));

__device__ __forceinline__ unsigned short f2bf(float f) {
    union { float f; unsigned u; } v; v.f = f;
    unsigned r = v.u + 0x7FFFu + ((v.u >> 16) & 1u);   // RNE
    return (unsigned short)(r >> 16);
}

__device__ __forceinline__ void gload_lds16(const void* g, void* l) {
    __builtin_amdgcn_global_load_lds(
        (const __attribute__((address_space(1))) void*)g,
        (__attribute__((address_space(3))) void*)l, 16, 0, 0);
}

// swizzled fragment read: tile rows are 32 bf16 (64 B); slot bits 3-4 XOR (R>>2)&3
__device__ __forceinline__ bf16x8 ldfrag32(const unsigned short* S, int R, int kb) {
    int off = R * 32 + (kb ^ (((R >> 2) & 3) << 3));
    return *reinterpret_cast<const bf16x8*>(S + off);
}

#define SWZ(row) ((((row) >> 2) & 3) << 3)

// ---------------- converts (write swizzled ws layouts) ----------------

// X fp32 -> Xb bf16 [8192][2048], 8-elem granule XOR-swizzled by (row>>2)&3
__global__ __launch_bounds__(256) void k_cvt_x(const float* __restrict__ X,
                                               unsigned short* __restrict__ Xb) {
    size_t base = ((size_t)blockIdx.x * 256 + threadIdx.x) * 8;
    int row = (int)(base >> 11);
    int k   = (int)(base & (HID - 1));
    int kp  = k ^ SWZ(row);
    float4 v0 = *reinterpret_cast<const float4*>(X + base);
    float4 v1 = *reinterpret_cast<const float4*>(X + base + 4);
    uint4 o;
    o.x = (unsigned)f2bf(v0.x) | ((unsigned)f2bf(v0.y) << 16);
    o.y = (unsigned)f2bf(v0.z) | ((unsigned)f2bf(v0.w) << 16);
    o.z = (unsigned)f2bf(v1.x) | ((unsigned)f2bf(v1.y) << 16);
    o.w = (unsigned)f2bf(v1.z) | ((unsigned)f2bf(v1.w) << 16);
    *reinterpret_cast<uint4*>(Xb + (size_t)row * HID + kp) = o;
}

// w1[e][h][2I] fp32 -> w1t[e][pc][h] bf16, pc = 2n + c (GLU interleave), swizzled
__global__ __launch_bounds__(256) void k_cvt_w1(const float* __restrict__ W1,
                                                unsigned short* __restrict__ W1T) {
    __shared__ unsigned short lds[64][72];
    const int bid = blockIdx.x;
    const int hb = bid % (HID / 64);
    const int pb = (bid / (HID / 64)) % (I2 / 64);
    const int e  = bid / ((HID / 64) * (I2 / 64));
    const int h0 = hb * 64, p0 = pb * 64, n0 = p0 >> 1;
    const float* w1e = W1 + (size_t)e * HID * I2;
    const int t = threadIdx.x;
#pragma unroll
    for (int it = 0; it < 16; ++it) {
        int lin   = it * 256 + t;
        int n_off = lin & 31;
        int c     = (lin >> 5) & 1;
        int h_off = lin >> 6;
        float v = w1e[(size_t)(h0 + h_off) * I2 + c * INTER + n0 + n_off];
        lds[2 * n_off + c][h_off] = f2bf(v);
    }
    __syncthreads();
    unsigned short* o = W1T + (size_t)e * I2 * HID;
#pragma unroll
    for (int it = 0; it < 4; ++it) {
        int lin = it * 256 + t;
        int r   = lin >> 4;
        int co  = (lin & 15) * 4;
        int cop = co ^ SWZ(r);
        ushort4 v = *reinterpret_cast<ushort4*>(&lds[r][co]);
        *reinterpret_cast<ushort4*>(o + (size_t)(p0 + r) * HID + h0 + cop) = v;
    }
}

// w2[e][i][H] fp32 -> w2t[e][h][i] bf16, swizzled
__global__ __launch_bounds__(256) void k_cvt_w2(const float* __restrict__ W2,
                                                unsigned short* __restrict__ W2T) {
    __shared__ unsigned short lds[64][72];
    const int bid = blockIdx.x;
    const int ib = bid % (INTER / 64);
    const int hb = (bid / (INTER / 64)) % (HID / 64);
    const int e  = bid / ((INTER / 64) * (HID / 64));
    const int i0 = ib * 64, h0 = hb * 64;
    const float* w2e = W2 + (size_t)e * INTER * HID;
    const int t = threadIdx.x;
#pragma unroll
    for (int it = 0; it < 16; ++it) {
        int lin   = it * 256 + t;
        int h_off = lin & 63;
        int i_off = lin >> 6;
        float v = w2e[(size_t)(i0 + i_off) * HID + h0 + h_off];
        lds[h_off][i_off] = f2bf(v);
    }
    __syncthreads();
    unsigned short* o = W2T + (size_t)e * HID * INTER;
#pragma unroll
    for (int it = 0; it < 4; ++it) {
        int lin = it * 256 + t;
        int r   = lin >> 4;
        int co  = (lin & 15) * 4;
        int cop = co ^ SWZ(r);
        ushort4 v = *reinterpret_cast<ushort4*>(&lds[r][co]);
        *reinterpret_cast<ushort4*>(o + (size_t)(h0 + r) * INTER + i0 + cop) = v;
    }
}

// ---------------- 256x128 BK=32 8-wave GEMM core, 2 blocks/CU ----------------
// LDS (ushort offsets): A0=0 (8192), B0=8192 (4096), A1=12288, B1=20480.
// Stage per tile: 3 gload_lds/thread (A two 128-row passes + B one pass),
// dest = base + t*16B (wave-uniform + lane-linear, required by gload_lds).

__device__ __forceinline__ void stage_tile32(const unsigned short* Ab, const unsigned short* Bb,
                                             int ktot, int k0,
                                             unsigned short* Adst, unsigned short* Bdst,
                                             int t) {
    const int r = t >> 2;
    const int c = (t & 3) * 8;
    gload_lds16(Ab + (size_t)r * ktot + k0 + c,         Adst + t * 8);
    gload_lds16(Ab + (size_t)(128 + r) * ktot + k0 + c, Adst + 4096 + t * 8);
    gload_lds16(Bb + (size_t)r * ktot + k0 + c,         Bdst + t * 8);
}

#define MFMA_BF16(a, b, c) __builtin_amdgcn_mfma_f32_16x16x32_bf16(a, b, c, 0, 0, 0)
#define MEMFENCE asm volatile("" ::: "memory")

__device__ __forceinline__ void gemm_core32(const unsigned short* Ab, const unsigned short* Bb,
                                            int ktot, int nkt, f32x4 (&acc)[4][4],
                                            unsigned short* lds,
                                            int t, int lane, int wr, int wc) {
    unsigned short* Abuf[2] = { lds,         lds + 12288 };
    unsigned short* Bbuf[2] = { lds + 8192,  lds + 20480 };

    // prologue: tile0 -> buf0, tile1 -> buf1; wait tile0's 3, keep tile1's 3 in flight
    stage_tile32(Ab, Bb, ktot, 0,  Abuf[0], Bbuf[0], t);
    stage_tile32(Ab, Bb, ktot, 32, Abuf[1], Bbuf[1], t);
    asm volatile("s_waitcnt vmcnt(3)" ::: "memory");
    __builtin_amdgcn_s_barrier();
    MEMFENCE;

    const int cl  = lane & 15;
    const int kb0 = (lane >> 4) << 3;

    bf16x8 b[4];        // all B-frags for current tile
    bf16x8 areg[2];     // A-frag ping-pong

    // tile-0 operands
#pragma unroll
    for (int j = 0; j < 4; ++j)
        b[j] = ldfrag32(Bbuf[0], wc + j * 16 + cl, kb0);
    areg[0] = ldfrag32(Abuf[0], wr + cl, kb0);

    for (int kt = 0; kt < nkt; ++kt) {
        unsigned short* Ac = Abuf[kt & 1];

        // 4 micro-clusters: issue next A-frag read, then 4 MFMA on current
#pragma unroll
        for (int mf = 0; mf < 4; ++mf) {
            if (mf < 3)
                areg[(mf + 1) & 1] = ldfrag32(Ac, wr + (mf + 1) * 16 + cl, kb0);
            __builtin_amdgcn_s_setprio(1);
#pragma unroll
            for (int j = 0; j < 4; ++j)
                acc[mf][j] = MFMA_BF16(areg[mf & 1], b[j], acc[mf][j]);
            __builtin_amdgcn_s_setprio(0);
        }

        __builtin_amdgcn_s_barrier();      // all waves done reading buf kt&1
        MEMFENCE;

        if (kt + 2 < nkt) {
            stage_tile32(Ab, Bb, ktot, (kt + 2) * 32, Abuf[kt & 1], Bbuf[kt & 1], t);
            asm volatile("s_waitcnt vmcnt(3)" ::: "memory");   // tile kt+1 landed
        } else if (kt + 1 < nkt) {
            asm volatile("s_waitcnt vmcnt(0)" ::: "memory");
        }
        __builtin_amdgcn_s_barrier();
        MEMFENCE;

        if (kt + 1 < nkt) {
            unsigned short* An = Abuf[(kt + 1) & 1];
            unsigned short* Bn = Bbuf[(kt + 1) & 1];
#pragma unroll
            for (int j = 0; j < 4; ++j)
                b[j] = ldfrag32(Bn, wc + j * 16 + cl, kb0);
            areg[0] = ldfrag32(An, wr + cl, kb0);
        }
    }
}

// fc1: Xb @ w1t^T -> inter bf16 (GLU fused, swizzled store)
__global__ __launch_bounds__(512, 4) void k_fc1_8p(const unsigned short* __restrict__ Xb,
                                                   const unsigned short* __restrict__ W1T,
                                                   unsigned short* __restrict__ inter) {
    extern __shared__ unsigned short lds[];
    const int hw  = blockIdx.x;                // 2816 blocks = 8 XCDs * 352
    const int e   = hw & 7;                    // expert pinned to XCD
    const int idx = hw >> 3;                   // 0..351
    const int mt  = idx & 3;                   // mt innermost: B-panel shared x4
    const int nt  = idx >> 2;                  // 0..87
    const int t = threadIdx.x, lane = t & 63, w = t >> 6;
    const int wr = (w >> 1) * 64;              // 4 M row-groups
    const int wc = (w & 1) * 64;               // 2 N col-groups
    const int m0 = e * TOK + mt * 256;
    const int n0 = nt * 128;                   // pc-space
    const unsigned short* Ab = Xb  + (size_t)m0 * HID;
    const unsigned short* Bb = W1T + (size_t)e * I2 * HID + (size_t)n0 * HID;

    f32x4 acc[4][4];
#pragma unroll
    for (int i = 0; i < 4; ++i)
#pragma unroll
        for (int j = 0; j < 4; ++j) acc[i][j] = f32x4{0.f, 0.f, 0.f, 0.f};

    gemm_core32(Ab, Bb, HID, HID / 32, acc, lds, t, lane, wr, wc);

    // epilogue: adjacent pc lanes hold (a,b); even lanes store silu(a)*b
    const int cl = lane & 15;
    const int r0 = (lane >> 4) << 2;
#pragma unroll
    for (int mf = 0; mf < 4; ++mf)
#pragma unroll
        for (int nf = 0; nf < 4; ++nf)
#pragma unroll
            for (int r = 0; r < 4; ++r) {
                float v  = acc[mf][nf][r];
                float pv = __shfl_xor(v, 1);
                if ((lane & 1) == 0) {
                    float s = v / (1.f + __expf(-v)) * pv;
                    int row = m0 + wr + mf * 16 + r0 + r;
                    int pc  = n0 + wc + nf * 16 + cl;
                    int c   = pc >> 1;
                    int c2  = (c & ~31) | ((c & 31) ^ SWZ(row));  // fc2-A swizzle
                    inter[(size_t)row * INTER + c2] = f2bf(s);
                }
            }
}

// fc2: inter @ w2t^T -> out fp32
__global__ __launch_bounds__(512, 4) void k_fc2_8p(const unsigned short* __restrict__ A,
                                                   const unsigned short* __restrict__ W2T,
                                                   float* __restrict__ out) {
    extern __shared__ unsigned short lds[];
    const int hw  = blockIdx.x;                // 512 blocks = 8 XCDs * 64
    const int e   = hw & 7;
    const int idx = hw >> 3;                   // 0..63
    const int mt  = idx & 3;
    const int nt  = idx >> 2;                  // 0..15
    const int t = threadIdx.x, lane = t & 63, w = t >> 6;
    const int wr = (w >> 1) * 64;
    const int wc = (w & 1) * 64;
    const int m0 = e * TOK + mt * 256;
    const int n0 = nt * 128;
    const unsigned short* Ab = A   + (size_t)m0 * INTER;
    const unsigned short* Bb = W2T + (size_t)e * HID * INTER + (size_t)n0 * INTER;

    f32x4 acc[4][4];
#pragma unroll
    for (int i = 0; i < 4; ++i)
#pragma unroll
        for (int j = 0; j < 4; ++j) acc[i][j] = f32x4{0.f, 0.f, 0.f, 0.f};

    gemm_core32(Ab, Bb, INTER, INTER / 32, acc, lds, t, lane, wr, wc);

    const int cl = lane & 15;
    const int r0 = (lane >> 4) << 2;
#pragma unroll
    for (int mf = 0; mf < 4; ++mf)
#pragma unroll
        for (int nf = 0; nf < 4; ++nf)
#pragma unroll
            for (int r = 0; r < 4; ++r) {
                int row = m0 + wr + mf * 16 + r0 + r;
                int col = n0 + wc + nf * 16 + cl;
                out[(size_t)row * HID + col] = acc[mf][nf][r];
            }
}

// ---------------- fallback (round-1 kernels, need only 92 MB ws) ----------------

#define BM  128
#define BK  64
#define LDK 72

__global__ __launch_bounds__(256) void k_fc1_glu_fb(
    const float* __restrict__ X, const float* __restrict__ W1,
    unsigned short* __restrict__ inter)
{
    __shared__ unsigned short As[BM][LDK];
    __shared__ unsigned short Bs[128][LDK];
    const int bid = blockIdx.x;
    const int nt  = bid % (INTER / 64);
    const int mt  = (bid / (INTER / 64)) % (TOK / BM);
    const int e   = bid / ((INTER / 64) * (TOK / BM));
    const int t = threadIdx.x, lane = t & 63, w = t >> 6;
    const int m0 = mt * BM;
    const int rowbase = e * TOK + m0;
    f32x4 acc[2][8];
#pragma unroll
    for (int i = 0; i < 2; ++i)
#pragma unroll
        for (int jj = 0; jj < 8; ++jj) acc[i][jj] = f32x4{0.f, 0.f, 0.f, 0.f};
    const int jcol = t & 127;
    const int hf   = t >> 7;
    const int gcol = (jcol < 64) ? (nt * 64 + jcol) : (INTER + nt * 64 + (jcol - 64));
    const float* w1e = W1 + (size_t)e * HID * I2;
    for (int k0 = 0; k0 < HID; k0 += BK) {
#pragma unroll
        for (int it = 0; it < 8; ++it) {
            int lin = it * 256 + t;
            int r   = lin >> 4;
            int kq  = (lin & 15) << 2;
            const float4 v = *reinterpret_cast<const float4*>(
                X + (size_t)(rowbase + r) * HID + k0 + kq);
            ushort4 o;
            o.x = f2bf(v.x); o.y = f2bf(v.y); o.z = f2bf(v.z); o.w = f2bf(v.w);
            *reinterpret_cast<ushort4*>(&As[r][kq]) = o;
        }
#pragma unroll
        for (int it = 0; it < 8; ++it) {
            int kq = hf * 4 + it * 8;
            const float* p = w1e + (size_t)(k0 + kq) * I2 + gcol;
            float v0 = p[0], v1 = p[I2], v2 = p[2 * I2], v3 = p[3 * I2];
            ushort4 o;
            o.x = f2bf(v0); o.y = f2bf(v1); o.z = f2bf(v2); o.w = f2bf(v3);
            *reinterpret_cast<ushort4*>(&Bs[jcol][kq]) = o;
        }
        __syncthreads();
#pragma unroll
        for (int kk = 0; kk < 2; ++kk) {
            const int kb = kk * 32 + ((lane >> 4) << 3);
            bf16x8 a0 = *reinterpret_cast<const bf16x8*>(&As[w * 32 + (lane & 15)][kb]);
            bf16x8 a1 = *reinterpret_cast<const bf16x8*>(&As[w * 32 + 16 + (lane & 15)][kb]);
#pragma unroll
            for (int nf = 0; nf < 8; ++nf) {
                bf16x8 b = *reinterpret_cast<const bf16x8*>(&Bs[nf * 16 + (lane & 15)][kb]);
                acc[0][nf] = MFMA_BF16(a0, b, acc[0][nf]);
                acc[1][nf] = MFMA_BF16(a1, b, acc[1][nf]);
            }
        }
        __syncthreads();
    }
    const int rl0 = w * 32 + ((lane >> 4) << 2);
    const int cl  = lane & 15;
#pragma unroll
    for (int mf = 0; mf < 2; ++mf)
#pragma unroll
        for (int nfa = 0; nfa < 4; ++nfa) {
            f32x4 va = acc[mf][nfa];
            f32x4 vb = acc[mf][nfa + 4];
#pragma unroll
            for (int r = 0; r < 4; ++r) {
                float a = va[r], b = vb[r];
                float s = a / (1.f + __expf(-a)) * b;
                int row = rowbase + rl0 + mf * 16 + r;
                int col = nt * 64 + nfa * 16 + cl;
                inter[(size_t)row * INTER + col] = f2bf(s);
            }
        }
}

__global__ __launch_bounds__(256) void k_fc2_fb(
    const unsigned short* __restrict__ inter, const float* __restrict__ W2,
    float* __restrict__ out)
{
    __shared__ unsigned short As[BM][LDK];
    __shared__ unsigned short Bs[128][LDK];
    const int bid = blockIdx.x;
    const int nt  = bid % (HID / 128);
    const int mt  = (bid / (HID / 128)) % (TOK / BM);
    const int e   = bid / ((HID / 128) * (TOK / BM));
    const int t = threadIdx.x, lane = t & 63, w = t >> 6;
    const int m0 = mt * BM;
    const int rowbase = e * TOK + m0;
    f32x4 acc[2][8];
#pragma unroll
    for (int i = 0; i < 2; ++i)
#pragma unroll
        for (int jj = 0; jj < 8; ++jj) acc[i][jj] = f32x4{0.f, 0.f, 0.f, 0.f};
    const int jcol = t & 127;
    const int hf   = t >> 7;
    const int gcol = nt * 128 + jcol;
    const float* w2e = W2 + (size_t)e * INTER * HID;
    for (int k0 = 0; k0 < INTER; k0 += BK) {
#pragma unroll
        for (int it = 0; it < 4; ++it) {
            int lin = it * 256 + t;
            int r   = lin >> 3;
            int kq  = (lin & 7) << 3;
            uint4 v = *reinterpret_cast<const uint4*>(
                inter + (size_t)(rowbase + r) * INTER + k0 + kq);
            *reinterpret_cast<uint4*>(&As[r][kq]) = v;
        }
#pragma unroll
        for (int it = 0; it < 8; ++it) {
            int kq = hf * 4 + it * 8;
            const float* p = w2e + (size_t)(k0 + kq) * HID + gcol;
            float v0 = p[0], v1 = p[HID], v2 = p[2 * HID], v3 = p[3 * HID];
            ushort4 o;
            o.x = f2bf(v0); o.y = f2bf(v1); o.z = f2bf(v2); o.w = f2bf(v3);
            *reinterpret_cast<ushort4*>(&Bs[jcol][kq]) = o;
        }
        __syncthreads();
#pragma unroll
        for (int kk = 0; kk < 2; ++kk) {
            const int kb = kk * 32 + ((lane >> 4) << 3);
            bf16x8 a0 = *reinterpret_cast<const bf16x8*>(&As[w * 32 + (lane & 15)][kb]);
            bf16x8 a1 = *reinterpret_cast<const bf16x8*>(&As[w * 32 + 16 + (lane & 15)][kb]);
#pragma unroll
            for (int nf = 0; nf < 8; ++nf) {
                bf16x8 b = *reinterpret_cast<const bf16x8*>(&Bs[nf * 16 + (lane & 15)][kb]);
                acc[0][nf] = MFMA_BF16(a0, b, acc[0][nf]);
                acc[1][nf] = MFMA_BF16(a1, b, acc[1][nf]);
            }
        }
        __syncthreads();
    }
    const int rl0 = w * 32 + ((lane >> 4) << 2);
    const int cl  = lane & 15;
#pragma unroll
    for (int mf = 0; mf < 2; ++mf)
#pragma unroll
        for (int nf = 0; nf < 8; ++nf) {
            f32x4 v = acc[mf][nf];
#pragma unroll
            for (int r = 0; r < 4; ++r) {
                int row = rowbase + rl0 + mf * 16 + r;
                int col = nt * 128 + nf * 16 + cl;
                out[(size_t)row * HID + col] = v[r];
            }
        }
}

// ---------------- launch ----------------

extern "C" void kernel_launch(void* const* d_in, const int* in_sizes, int n_in,
                              void* d_out, int out_size, void* d_ws, size_t ws_size,
                              hipStream_t stream) {
    const float* X  = (const float*)d_in[0];
    const float* W1 = (const float*)d_in[1];
    const float* W2 = (const float*)d_in[2];
    float* out = (float*)d_out;

    const size_t XB_B  = (size_t)EXPERTS * TOK * HID * 2;
    const size_t W1T_B = (size_t)EXPERTS * I2 * HID * 2;
    const size_t W2T_B = (size_t)EXPERTS * HID * INTER * 2;
    const size_t INT_B = (size_t)EXPERTS * TOK * INTER * 2;
    const size_t need  = XB_B + W1T_B + W2T_B + INT_B;

    if (ws_size >= need) {
        unsigned short* Xb    = (unsigned short*)d_ws;
        unsigned short* w1t   = (unsigned short*)((char*)d_ws + XB_B);
        unsigned short* w2t   = (unsigned short*)((char*)d_ws + XB_B + W1T_B);
        unsigned short* inter = (unsigned short*)((char*)d_ws + XB_B + W1T_B + W2T_B);

        hipFuncSetAttribute((const void*)k_fc1_8p,
            hipFuncAttributeMaxDynamicSharedMemorySize, 49152);
        hipFuncSetAttribute((const void*)k_fc2_8p,
            hipFuncAttributeMaxDynamicSharedMemorySize, 49152);

        dim3 b256(256), b512(512);
        k_cvt_x <<<(EXPERTS * TOK * HID) / (256 * 8), b256, 0, stream>>>(X, Xb);
        k_cvt_w1<<<EXPERTS * (I2 / 64) * (HID / 64),   b256, 0, stream>>>(W1, w1t);
        k_cvt_w2<<<EXPERTS * (HID / 64) * (INTER / 64), b256, 0, stream>>>(W2, w2t);
        k_fc1_8p<<<EXPERTS * 4 * (I2 / 128),  b512, 49152, stream>>>(Xb, w1t, inter);
        k_fc2_8p<<<EXPERTS * 4 * (HID / 128), b512, 49152, stream>>>(inter, w2t, out);
    } else {
        unsigned short* inter = (unsigned short*)d_ws;
        dim3 b256(256);
        k_fc1_glu_fb<<<EXPERTS * (TOK / BM) * (INTER / 64), b256, 0, stream>>>(X, W1, inter);
        k_fc2_fb    <<<EXPERTS * (TOK / BM) * (HID / 128),  b256, 0, stream>>>(inter, W2, out);
    }
}

// Round 8
// 1263.556 us; speedup vs baseline: 1.0411x; 1.0411x over previous
//
#include <hip/hip_runtime.h>
#include <hip/hip_bf16.h>

// GroupedMLP: E=8, T=1024, H=2048, I=5632
// Round 8: round-2's verified m97-structure GEMMs (128x128 tile, 4 waves,
// single-buffer LDS, global_load_lds w16, 2-barrier K-loop — the structure
// measured 874-912 TF in learn_hip) with ONE change vs round 2: block order
// is expert-per-XCD + mt-innermost (round-4's proven L2 fix), so B-panels
// are shared by the 8 co-resident mt-blocks and the per-expert A working set
// (4 MB) lives in the XCD's L2. r2's loss was K-tile drains waiting on HBM
// (~900cyc) instead of L2 (~200cyc); with ~4 blocks/CU, drain latency sets
// MfmaUtil.

#define EXPERTS 8
#define TOK     1024
#define HID     2048
#define INTER   5632
#define I2      (2 * INTER)

typedef __bf16 bf16x8 __attribute__((ext_vector_type(8)));
typedef float  f32x4  __attribute__((ext_vector_type(4)));

__device__ __forceinline__ unsigned short f2bf(float f) {
    union { float f; unsigned u; } v; v.f = f;
    unsigned r = v.u + 0x7FFFu + ((v.u >> 16) & 1u);   // RNE
    return (unsigned short)(r >> 16);
}

__device__ __forceinline__ void gload_lds16(const void* g, void* l) {
    __builtin_amdgcn_global_load_lds(
        (const __attribute__((address_space(1))) void*)g,
        (__attribute__((address_space(3))) void*)l, 16, 0, 0);
}

// ---------------- converts (plain layouts, as in round 2) ----------------

// X fp32 -> bf16, 8 elems/thread
__global__ __launch_bounds__(256) void k_cvt_x(const float* __restrict__ X,
                                               unsigned short* __restrict__ Xb) {
    size_t i = ((size_t)blockIdx.x * 256 + threadIdx.x) * 8;
    float4 v0 = *reinterpret_cast<const float4*>(X + i);
    float4 v1 = *reinterpret_cast<const float4*>(X + i + 4);
    uint4 o;
    o.x = (unsigned)f2bf(v0.x) | ((unsigned)f2bf(v0.y) << 16);
    o.y = (unsigned)f2bf(v0.z) | ((unsigned)f2bf(v0.w) << 16);
    o.z = (unsigned)f2bf(v1.x) | ((unsigned)f2bf(v1.y) << 16);
    o.w = (unsigned)f2bf(v1.z) | ((unsigned)f2bf(v1.w) << 16);
    *reinterpret_cast<uint4*>(Xb + i) = o;
}

// w1[e][h][2I] fp32 -> w1t[e][pc][h] bf16, pc = 2n + c where col = c*I + n
__global__ __launch_bounds__(256) void k_cvt_w1(const float* __restrict__ W1,
                                                unsigned short* __restrict__ W1T) {
    __shared__ unsigned short lds[64][72];
    const int bid = blockIdx.x;
    const int hb = bid % (HID / 64);
    const int pb = (bid / (HID / 64)) % (I2 / 64);
    const int e  = bid / ((HID / 64) * (I2 / 64));
    const int h0 = hb * 64, p0 = pb * 64, n0 = p0 >> 1;
    const float* w1e = W1 + (size_t)e * HID * I2;
    const int t = threadIdx.x;
#pragma unroll
    for (int it = 0; it < 16; ++it) {
        int lin   = it * 256 + t;
        int n_off = lin & 31;
        int c     = (lin >> 5) & 1;
        int h_off = lin >> 6;
        float v = w1e[(size_t)(h0 + h_off) * I2 + c * INTER + n0 + n_off];
        lds[2 * n_off + c][h_off] = f2bf(v);
    }
    __syncthreads();
    unsigned short* o = W1T + (size_t)e * I2 * HID;
#pragma unroll
    for (int it = 0; it < 4; ++it) {
        int lin = it * 256 + t;
        int r   = lin >> 4;
        int co  = (lin & 15) * 4;
        ushort4 v = *reinterpret_cast<ushort4*>(&lds[r][co]);
        *reinterpret_cast<ushort4*>(o + (size_t)(p0 + r) * HID + h0 + co) = v;
    }
}

// w2[e][i][H] fp32 -> w2t[e][h][i] bf16 (plain transpose)
__global__ __launch_bounds__(256) void k_cvt_w2(const float* __restrict__ W2,
                                                unsigned short* __restrict__ W2T) {
    __shared__ unsigned short lds[64][72];
    const int bid = blockIdx.x;
    const int ib = bid % (INTER / 64);
    const int hb = (bid / (INTER / 64)) % (HID / 64);
    const int e  = bid / ((INTER / 64) * (HID / 64));
    const int i0 = ib * 64, h0 = hb * 64;
    const float* w2e = W2 + (size_t)e * INTER * HID;
    const int t = threadIdx.x;
#pragma unroll
    for (int it = 0; it < 16; ++it) {
        int lin   = it * 256 + t;
        int h_off = lin & 63;
        int i_off = lin >> 6;
        float v = w2e[(size_t)(i0 + i_off) * HID + h0 + h_off];
        lds[h_off][i_off] = f2bf(v);
    }
    __syncthreads();
    unsigned short* o = W2T + (size_t)e * HID * INTER;
#pragma unroll
    for (int it = 0; it < 4; ++it) {
        int lin = it * 256 + t;
        int r   = lin >> 4;
        int co  = (lin & 15) * 4;
        ushort4 v = *reinterpret_cast<ushort4*>(&lds[r][co]);
        *reinterpret_cast<ushort4*>(o + (size_t)(h0 + r) * INTER + i0 + co) = v;
    }
}

#define MFMA_BF16(a, b, c) __builtin_amdgcn_mfma_f32_16x16x32_bf16(a, b, c, 0, 0, 0)

// ---------------- m97-structure GEMMs (round-2 verbatim, new block order) ----

// fc1: Xb[8192][2048] @ w1t^T -> inter bf16 with fused GLU
__global__ __launch_bounds__(256) void k_fc1(const unsigned short* __restrict__ A,
                                             const unsigned short* __restrict__ BT,
                                             unsigned short* __restrict__ Cinter) {
    __shared__ unsigned short As[128 * 64];
    __shared__ unsigned short Bs[128 * 64];
    const int bid = blockIdx.x;            // 5632 = 8 XCD * 704
    const int e   = bid & 7;               // expert pinned to XCD
    const int idx = bid >> 3;              // 0..703
    const int mt  = idx & 7;               // mt innermost: 8 blocks share B-panel
    const int nt  = idx >> 3;              // 0..87
    const int t = threadIdx.x, lane = t & 63, w = t >> 6;
    const int m0 = e * TOK + mt * 128;
    const int n0 = nt * 128;
    const unsigned short* Ab = A + (size_t)m0 * HID;
    const unsigned short* Bb = BT + (size_t)e * I2 * HID + (size_t)n0 * HID;

    f32x4 acc[4][4];
#pragma unroll
    for (int i = 0; i < 4; ++i)
#pragma unroll
        for (int j = 0; j < 4; ++j) acc[i][j] = f32x4{0.f, 0.f, 0.f, 0.f};

    const int srow = lane >> 3;        // 0..7
    const int scol = (lane & 7) * 8;   // element offset (16B per lane)

    for (int k0 = 0; k0 < HID; k0 += 64) {
#pragma unroll
        for (int i = 0; i < 4; ++i) {
            int j   = w * 4 + i;       // staging instr 0..15
            int row = j * 8 + srow;
            gload_lds16(Ab + (size_t)row * HID + k0 + scol, (void*)(As + j * 512));
            gload_lds16(Bb + (size_t)row * HID + k0 + scol, (void*)(Bs + j * 512));
        }
        __syncthreads();
        const int wr = (w >> 1) * 64, wc = (w & 1) * 64;
#pragma unroll
        for (int kk = 0; kk < 2; ++kk) {
            const int kb = kk * 32 + ((lane >> 4) << 3);
            bf16x8 a[4], b[4];
#pragma unroll
            for (int mf = 0; mf < 4; ++mf)
                a[mf] = *reinterpret_cast<const bf16x8*>(As + (wr + mf * 16 + (lane & 15)) * 64 + kb);
#pragma unroll
            for (int nf = 0; nf < 4; ++nf)
                b[nf] = *reinterpret_cast<const bf16x8*>(Bs + (wc + nf * 16 + (lane & 15)) * 64 + kb);
#pragma unroll
            for (int mf = 0; mf < 4; ++mf)
#pragma unroll
                for (int nf = 0; nf < 4; ++nf)
                    acc[mf][nf] = MFMA_BF16(a[mf], b[nf], acc[mf][nf]);
        }
        __syncthreads();
    }

    // epilogue: adjacent pc lanes hold (a,b); even lanes store silu(a)*b
    const int wr = (w >> 1) * 64, wc = (w & 1) * 64;
    const int cl = lane & 15;
#pragma unroll
    for (int mf = 0; mf < 4; ++mf)
#pragma unroll
        for (int nf = 0; nf < 4; ++nf)
#pragma unroll
            for (int r = 0; r < 4; ++r) {
                float v  = acc[mf][nf][r];
                float pv = __shfl_xor(v, 1);
                if ((lane & 1) == 0) {
                    float s = v / (1.f + __expf(-v)) * pv;
                    int row = m0 + wr + mf * 16 + ((lane >> 4) << 2) + r;
                    int pc  = n0 + wc + nf * 16 + cl;
                    Cinter[(size_t)row * INTER + (pc >> 1)] = f2bf(s);
                }
            }
}

// fc2: inter[8192][5632] @ w2t^T -> out fp32
__global__ __launch_bounds__(256) void k_fc2n(const unsigned short* __restrict__ A,
                                              const unsigned short* __restrict__ BT,
                                              float* __restrict__ out) {
    __shared__ unsigned short As[128 * 64];
    __shared__ unsigned short Bs[128 * 64];
    const int bid = blockIdx.x;            // 1024 = 8 XCD * 128
    const int e   = bid & 7;
    const int idx = bid >> 3;              // 0..127
    const int mt  = idx & 7;               // mt innermost
    const int nt  = idx >> 3;              // 0..15
    const int t = threadIdx.x, lane = t & 63, w = t >> 6;
    const int m0 = e * TOK + mt * 128;
    const int n0 = nt * 128;
    const unsigned short* Ab = A + (size_t)m0 * INTER;
    const unsigned short* Bb = BT + (size_t)e * HID * INTER + (size_t)n0 * INTER;

    f32x4 acc[4][4];
#pragma unroll
    for (int i = 0; i < 4; ++i)
#pragma unroll
        for (int j = 0; j < 4; ++j) acc[i][j] = f32x4{0.f, 0.f, 0.f, 0.f};

    const int srow = lane >> 3;
    const int scol = (lane & 7) * 8;

    for (int k0 = 0; k0 < INTER; k0 += 64) {
#pragma unroll
        for (int i = 0; i < 4; ++i) {
            int j   = w * 4 + i;
            int row = j * 8 + srow;
            gload_lds16(Ab + (size_t)row * INTER + k0 + scol, (void*)(As + j * 512));
            gload_lds16(Bb + (size_t)row * INTER + k0 + scol, (void*)(Bs + j * 512));
        }
        __syncthreads();
        const int wr = (w >> 1) * 64, wc = (w & 1) * 64;
#pragma unroll
        for (int kk = 0; kk < 2; ++kk) {
            const int kb = kk * 32 + ((lane >> 4) << 3);
            bf16x8 a[4], b[4];
#pragma unroll
            for (int mf = 0; mf < 4; ++mf)
                a[mf] = *reinterpret_cast<const bf16x8*>(As + (wr + mf * 16 + (lane & 15)) * 64 + kb);
#pragma unroll
            for (int nf = 0; nf < 4; ++nf)
                b[nf] = *reinterpret_cast<const bf16x8*>(Bs + (wc + nf * 16 + (lane & 15)) * 64 + kb);
#pragma unroll
            for (int mf = 0; mf < 4; ++mf)
#pragma unroll
                for (int nf = 0; nf < 4; ++nf)
                    acc[mf][nf] = MFMA_BF16(a[mf], b[nf], acc[mf][nf]);
        }
        __syncthreads();
    }

    const int wr = (w >> 1) * 64, wc = (w & 1) * 64;
    const int cl = lane & 15;
#pragma unroll
    for (int mf = 0; mf < 4; ++mf)
#pragma unroll
        for (int nf = 0; nf < 4; ++nf)
#pragma unroll
            for (int r = 0; r < 4; ++r) {
                int row = m0 + wr + mf * 16 + ((lane >> 4) << 2) + r;
                int col = n0 + wc + nf * 16 + cl;
                out[(size_t)row * HID + col] = acc[mf][nf][r];
            }
}

// ---------------- fallback (round-1 kernels, need only 92 MB ws) ----------------

#define BM  128
#define BK  64
#define LDK 72

__global__ __launch_bounds__(256) void k_fc1_glu_fb(
    const float* __restrict__ X, const float* __restrict__ W1,
    unsigned short* __restrict__ inter)
{
    __shared__ unsigned short As[BM][LDK];
    __shared__ unsigned short Bs[128][LDK];
    const int bid = blockIdx.x;
    const int nt  = bid % (INTER / 64);
    const int mt  = (bid / (INTER / 64)) % (TOK / BM);
    const int e   = bid / ((INTER / 64) * (TOK / BM));
    const int t = threadIdx.x, lane = t & 63, w = t >> 6;
    const int m0 = mt * BM;
    const int rowbase = e * TOK + m0;
    f32x4 acc[2][8];
#pragma unroll
    for (int i = 0; i < 2; ++i)
#pragma unroll
        for (int jj = 0; jj < 8; ++jj) acc[i][jj] = f32x4{0.f, 0.f, 0.f, 0.f};
    const int jcol = t & 127;
    const int hf   = t >> 7;
    const int gcol = (jcol < 64) ? (nt * 64 + jcol) : (INTER + nt * 64 + (jcol - 64));
    const float* w1e = W1 + (size_t)e * HID * I2;
    for (int k0 = 0; k0 < HID; k0 += BK) {
#pragma unroll
        for (int it = 0; it < 8; ++it) {
            int lin = it * 256 + t;
            int r   = lin >> 4;
            int kq  = (lin & 15) << 2;
            const float4 v = *reinterpret_cast<const float4*>(
                X + (size_t)(rowbase + r) * HID + k0 + kq);
            ushort4 o;
            o.x = f2bf(v.x); o.y = f2bf(v.y); o.z = f2bf(v.z); o.w = f2bf(v.w);
            *reinterpret_cast<ushort4*>(&As[r][kq]) = o;
        }
#pragma unroll
        for (int it = 0; it < 8; ++it) {
            int kq = hf * 4 + it * 8;
            const float* p = w1e + (size_t)(k0 + kq) * I2 + gcol;
            float v0 = p[0], v1 = p[I2], v2 = p[2 * I2], v3 = p[3 * I2];
            ushort4 o;
            o.x = f2bf(v0); o.y = f2bf(v1); o.z = f2bf(v2); o.w = f2bf(v3);
            *reinterpret_cast<ushort4*>(&Bs[jcol][kq]) = o;
        }
        __syncthreads();
#pragma unroll
        for (int kk = 0; kk < 2; ++kk) {
            const int kb = kk * 32 + ((lane >> 4) << 3);
            bf16x8 a0 = *reinterpret_cast<const bf16x8*>(&As[w * 32 + (lane & 15)][kb]);
            bf16x8 a1 = *reinterpret_cast<const bf16x8*>(&As[w * 32 + 16 + (lane & 15)][kb]);
#pragma unroll
            for (int nf = 0; nf < 8; ++nf) {
                bf16x8 b = *reinterpret_cast<const bf16x8*>(&Bs[nf * 16 + (lane & 15)][kb]);
                acc[0][nf] = MFMA_BF16(a0, b, acc[0][nf]);
                acc[1][nf] = MFMA_BF16(a1, b, acc[1][nf]);
            }
        }
        __syncthreads();
    }
    const int rl0 = w * 32 + ((lane >> 4) << 2);
    const int cl  = lane & 15;
#pragma unroll
    for (int mf = 0; mf < 2; ++mf)
#pragma unroll
        for (int nfa = 0; nfa < 4; ++nfa) {
            f32x4 va = acc[mf][nfa];
            f32x4 vb = acc[mf][nfa + 4];
#pragma unroll
            for (int r = 0; r < 4; ++r) {
                float a = va[r], b = vb[r];
                float s = a / (1.f + __expf(-a)) * b;
                int row = rowbase + rl0 + mf * 16 + r;
                int col = nt * 64 + nfa * 16 + cl;
                inter[(size_t)row * INTER + col] = f2bf(s);
            }
        }
}

__global__ __launch_bounds__(256) void k_fc2_fb(
    const unsigned short* __restrict__ inter, const float* __restrict__ W2,
    float* __restrict__ out)
{
    __shared__ unsigned short As[BM][LDK];
    __shared__ unsigned short Bs[128][LDK];
    const int bid = blockIdx.x;
    const int nt  = bid % (HID / 128);
    const int mt  = (bid / (HID / 128)) % (TOK / BM);
    const int e   = bid / ((HID / 128) * (TOK / BM));
    const int t = threadIdx.x, lane = t & 63, w = t >> 6;
    const int m0 = mt * BM;
    const int rowbase = e * TOK + m0;
    f32x4 acc[2][8];
#pragma unroll
    for (int i = 0; i < 2; ++i)
#pragma unroll
        for (int jj = 0; jj < 8; ++jj) acc[i][jj] = f32x4{0.f, 0.f, 0.f, 0.f};
    const int jcol = t & 127;
    const int hf   = t >> 7;
    const int gcol = nt * 128 + jcol;
    const float* w2e = W2 + (size_t)e * INTER * HID;
    for (int k0 = 0; k0 < INTER; k0 += BK) {
#pragma unroll
        for (int it = 0; it < 4; ++it) {
            int lin = it * 256 + t;
            int r   = lin >> 3;
            int kq  = (lin & 7) << 3;
            uint4 v = *reinterpret_cast<const uint4*>(
                inter + (size_t)(rowbase + r) * INTER + k0 + kq);
            *reinterpret_cast<uint4*>(&As[r][kq]) = v;
        }
#pragma unroll
        for (int it = 0; it < 8; ++it) {
            int kq = hf * 4 + it * 8;
            const float* p = w2e + (size_t)(k0 + kq) * HID + gcol;
            float v0 = p[0], v1 = p[HID], v2 = p[2 * HID], v3 = p[3 * HID];
            ushort4 o;
            o.x = f2bf(v0); o.y = f2bf(v1); o.z = f2bf(v2); o.w = f2bf(v3);
            *reinterpret_cast<ushort4*>(&Bs[jcol][kq]) = o;
        }
        __syncthreads();
#pragma unroll
        for (int kk = 0; kk < 2; ++kk) {
            const int kb = kk * 32 + ((lane >> 4) << 3);
            bf16x8 a0 = *reinterpret_cast<const bf16x8*>(&As[w * 32 + (lane & 15)][kb]);
            bf16x8 a1 = *reinterpret_cast<const bf16x8*>(&As[w * 32 + 16 + (lane & 15)][kb]);
#pragma unroll
            for (int nf = 0; nf < 8; ++nf) {
                bf16x8 b = *reinterpret_cast<const bf16x8*>(&Bs[nf * 16 + (lane & 15)][kb]);
                acc[0][nf] = MFMA_BF16(a0, b, acc[0][nf]);
                acc[1][nf] = MFMA_BF16(a1, b, acc[1][nf]);
            }
        }
        __syncthreads();
    }
    const int rl0 = w * 32 + ((lane >> 4) << 2);
    const int cl  = lane & 15;
#pragma unroll
    for (int mf = 0; mf < 2; ++mf)
#pragma unroll
        for (int nf = 0; nf < 8; ++nf) {
            f32x4 v = acc[mf][nf];
#pragma unroll
            for (int r = 0; r < 4; ++r) {
                int row = rowbase + rl0 + mf * 16 + r;
                int col = nt * 128 + nf * 16 + cl;
                out[(size_t)row * HID + col] = v[r];
            }
        }
}

// ---------------- launch ----------------

extern "C" void kernel_launch(void* const* d_in, const int* in_sizes, int n_in,
                              void* d_out, int out_size, void* d_ws, size_t ws_size,
                              hipStream_t stream) {
    const float* X  = (const float*)d_in[0];
    const float* W1 = (const float*)d_in[1];
    const float* W2 = (const float*)d_in[2];
    float* out = (float*)d_out;

    const size_t XB_B  = (size_t)EXPERTS * TOK * HID * 2;
    const size_t W1T_B = (size_t)EXPERTS * I2 * HID * 2;
    const size_t W2T_B = (size_t)EXPERTS * HID * INTER * 2;
    const size_t INT_B = (size_t)EXPERTS * TOK * INTER * 2;
    const size_t need  = XB_B + W1T_B + W2T_B + INT_B;

    dim3 blk(256);
    if (ws_size >= need) {
        unsigned short* Xb    = (unsigned short*)d_ws;
        unsigned short* w1t   = (unsigned short*)((char*)d_ws + XB_B);
        unsigned short* w2t   = (unsigned short*)((char*)d_ws + XB_B + W1T_B);
        unsigned short* inter = (unsigned short*)((char*)d_ws + XB_B + W1T_B + W2T_B);

        k_cvt_x <<<(EXPERTS * TOK * HID) / (256 * 8), blk, 0, stream>>>(X, Xb);
        k_cvt_w1<<<EXPERTS * (I2 / 64) * (HID / 64),  blk, 0, stream>>>(W1, w1t);
        k_cvt_w2<<<EXPERTS * (HID / 64) * (INTER / 64), blk, 0, stream>>>(W2, w2t);
        k_fc1   <<<EXPERTS * (TOK / 128) * (I2 / 128),  blk, 0, stream>>>(Xb, w1t, inter);
        k_fc2n  <<<EXPERTS * (TOK / 128) * (HID / 128), blk, 0, stream>>>(inter, w2t, out);
    } else {
        unsigned short* inter = (unsigned short*)d_ws;
        k_fc1_glu_fb<<<EXPERTS * (TOK / BM) * (INTER / 64), blk, 0, stream>>>(X, W1, inter);
        k_fc2_fb    <<<EXPERTS * (TOK / BM) * (HID / 128),  blk, 0, stream>>>(inter, W2, out);
    }
}

// Round 9
// 1261.189 us; speedup vs baseline: 1.0430x; 1.0019x over previous
//
#include <hip/hip_runtime.h>
#include <hip/hip_bf16.h>

// GroupedMLP: E=8, T=1024, H=2048, I=5632
// Round 8: round-2's verified m97-structure GEMMs (128x128 tile, 4 waves,
// single-buffer LDS, global_load_lds w16, 2-barrier K-loop — the structure
// measured 874-912 TF in learn_hip) with ONE change vs round 2: block order
// is expert-per-XCD + mt-innermost (round-4's proven L2 fix), so B-panels
// are shared by the 8 co-resident mt-blocks and the per-expert A working set
// (4 MB) lives in the XCD's L2. r2's loss was K-tile drains waiting on HBM
// (~900cyc) instead of L2 (~200cyc); with ~4 blocks/CU, drain latency sets
// MfmaUtil.

#define EXPERTS 8
#define TOK     1024
#define HID     2048
#define INTER   5632
#define I2      (2 * INTER)

typedef __bf16 bf16x8 __attribute__((ext_vector_type(8)));
typedef float  f32x4  __attribute__((ext_vector_type(4)));

__device__ __forceinline__ unsigned short f2bf(float f) {
    union { float f; unsigned u; } v; v.f = f;
    unsigned r = v.u + 0x7FFFu + ((v.u >> 16) & 1u);   // RNE
    return (unsigned short)(r >> 16);
}

__device__ __forceinline__ void gload_lds16(const void* g, void* l) {
    __builtin_amdgcn_global_load_lds(
        (const __attribute__((address_space(1))) void*)g,
        (__attribute__((address_space(3))) void*)l, 16, 0, 0);
}

// ---------------- converts (plain layouts, as in round 2) ----------------

// X fp32 -> bf16, 8 elems/thread
__global__ __launch_bounds__(256) void k_cvt_x(const float* __restrict__ X,
                                               unsigned short* __restrict__ Xb) {
    size_t i = ((size_t)blockIdx.x * 256 + threadIdx.x) * 8;
    float4 v0 = *reinterpret_cast<const float4*>(X + i);
    float4 v1 = *reinterpret_cast<const float4*>(X + i + 4);
    uint4 o;
    o.x = (unsigned)f2bf(v0.x) | ((unsigned)f2bf(v0.y) << 16);
    o.y = (unsigned)f2bf(v0.z) | ((unsigned)f2bf(v0.w) << 16);
    o.z = (unsigned)f2bf(v1.x) | ((unsigned)f2bf(v1.y) << 16);
    o.w = (unsigned)f2bf(v1.z) | ((unsigned)f2bf(v1.w) << 16);
    *reinterpret_cast<uint4*>(Xb + i) = o;
}

// w1[e][h][2I] fp32 -> w1t[e][pc][h] bf16, pc = 2n + c where col = c*I + n
__global__ __launch_bounds__(256) void k_cvt_w1(const float* __restrict__ W1,
                                                unsigned short* __restrict__ W1T) {
    __shared__ unsigned short lds[64][72];
    const int bid = blockIdx.x;
    const int hb = bid % (HID / 64);
    const int pb = (bid / (HID / 64)) % (I2 / 64);
    const int e  = bid / ((HID / 64) * (I2 / 64));
    const int h0 = hb * 64, p0 = pb * 64, n0 = p0 >> 1;
    const float* w1e = W1 + (size_t)e * HID * I2;
    const int t = threadIdx.x;
#pragma unroll
    for (int it = 0; it < 16; ++it) {
        int lin   = it * 256 + t;
        int n_off = lin & 31;
        int c     = (lin >> 5) & 1;
        int h_off = lin >> 6;
        float v = w1e[(size_t)(h0 + h_off) * I2 + c * INTER + n0 + n_off];
        lds[2 * n_off + c][h_off] = f2bf(v);
    }
    __syncthreads();
    unsigned short* o = W1T + (size_t)e * I2 * HID;
#pragma unroll
    for (int it = 0; it < 4; ++it) {
        int lin = it * 256 + t;
        int r   = lin >> 4;
        int co  = (lin & 15) * 4;
        ushort4 v = *reinterpret_cast<ushort4*>(&lds[r][co]);
        *reinterpret_cast<ushort4*>(o + (size_t)(p0 + r) * HID + h0 + co) = v;
    }
}

// w2[e][i][H] fp32 -> w2t[e][h][i] bf16 (plain transpose)
__global__ __launch_bounds__(256) void k_cvt_w2(const float* __restrict__ W2,
                                                unsigned short* __restrict__ W2T) {
    __shared__ unsigned short lds[64][72];
    const int bid = blockIdx.x;
    const int ib = bid % (INTER / 64);
    const int hb = (bid / (INTER / 64)) % (HID / 64);
    const int e  = bid / ((INTER / 64) * (HID / 64));
    const int i0 = ib * 64, h0 = hb * 64;
    const float* w2e = W2 + (size_t)e * INTER * HID;
    const int t = threadIdx.x;
#pragma unroll
    for (int it = 0; it < 16; ++it) {
        int lin   = it * 256 + t;
        int h_off = lin & 63;
        int i_off = lin >> 6;
        float v = w2e[(size_t)(i0 + i_off) * HID + h0 + h_off];
        lds[h_off][i_off] = f2bf(v);
    }
    __syncthreads();
    unsigned short* o = W2T + (size_t)e * HID * INTER;
#pragma unroll
    for (int it = 0; it < 4; ++it) {
        int lin = it * 256 + t;
        int r   = lin >> 4;
        int co  = (lin & 15) * 4;
        ushort4 v = *reinterpret_cast<ushort4*>(&lds[r][co]);
        *reinterpret_cast<ushort4*>(o + (size_t)(h0 + r) * INTER + i0 + co) = v;
    }
}

#define MFMA_BF16(a, b, c) __builtin_amdgcn_mfma_f32_16x16x32_bf16(a, b, c, 0, 0, 0)

// ---------------- m97-structure GEMMs (round-2 verbatim, new block order) ----

// fc1: Xb[8192][2048] @ w1t^T -> inter bf16 with fused GLU
__global__ __launch_bounds__(256) void k_fc1(const unsigned short* __restrict__ A,
                                             const unsigned short* __restrict__ BT,
                                             unsigned short* __restrict__ Cinter) {
    __shared__ unsigned short As[128 * 64];
    __shared__ unsigned short Bs[128 * 64];
    const int bid = blockIdx.x;            // 5632 = 8 XCD * 704
    const int e   = bid & 7;               // expert pinned to XCD
    const int idx = bid >> 3;              // 0..703
    const int mt  = idx & 7;               // mt innermost: 8 blocks share B-panel
    const int nt  = idx >> 3;              // 0..87
    const int t = threadIdx.x, lane = t & 63, w = t >> 6;
    const int m0 = e * TOK + mt * 128;
    const int n0 = nt * 128;
    const unsigned short* Ab = A + (size_t)m0 * HID;
    const unsigned short* Bb = BT + (size_t)e * I2 * HID + (size_t)n0 * HID;

    f32x4 acc[4][4];
#pragma unroll
    for (int i = 0; i < 4; ++i)
#pragma unroll
        for (int j = 0; j < 4; ++j) acc[i][j] = f32x4{0.f, 0.f, 0.f, 0.f};

    const int srow = lane >> 3;        // 0..7
    const int scol = (lane & 7) * 8;   // element offset (16B per lane)

    for (int k0 = 0; k0 < HID; k0 += 64) {
#pragma unroll
        for (int i = 0; i < 4; ++i) {
            int j   = w * 4 + i;       // staging instr 0..15
            int row = j * 8 + srow;
            gload_lds16(Ab + (size_t)row * HID + k0 + scol, (void*)(As + j * 512));
            gload_lds16(Bb + (size_t)row * HID + k0 + scol, (void*)(Bs + j * 512));
        }
        __syncthreads();
        const int wr = (w >> 1) * 64, wc = (w & 1) * 64;
#pragma unroll
        for (int kk = 0; kk < 2; ++kk) {
            const int kb = kk * 32 + ((lane >> 4) << 3);
            bf16x8 a[4], b[4];
#pragma unroll
            for (int mf = 0; mf < 4; ++mf)
                a[mf] = *reinterpret_cast<const bf16x8*>(As + (wr + mf * 16 + (lane & 15)) * 64 + kb);
#pragma unroll
            for (int nf = 0; nf < 4; ++nf)
                b[nf] = *reinterpret_cast<const bf16x8*>(Bs + (wc + nf * 16 + (lane & 15)) * 64 + kb);
#pragma unroll
            for (int mf = 0; mf < 4; ++mf)
#pragma unroll
                for (int nf = 0; nf < 4; ++nf)
                    acc[mf][nf] = MFMA_BF16(a[mf], b[nf], acc[mf][nf]);
        }
        __syncthreads();
    }

    // epilogue: adjacent pc lanes hold (a,b); even lanes store silu(a)*b
    const int wr = (w >> 1) * 64, wc = (w & 1) * 64;
    const int cl = lane & 15;
#pragma unroll
    for (int mf = 0; mf < 4; ++mf)
#pragma unroll
        for (int nf = 0; nf < 4; ++nf)
#pragma unroll
            for (int r = 0; r < 4; ++r) {
                float v  = acc[mf][nf][r];
                float pv = __shfl_xor(v, 1);
                if ((lane & 1) == 0) {
                    float s = v / (1.f + __expf(-v)) * pv;
                    int row = m0 + wr + mf * 16 + ((lane >> 4) << 2) + r;
                    int pc  = n0 + wc + nf * 16 + cl;
                    Cinter[(size_t)row * INTER + (pc >> 1)] = f2bf(s);
                }
            }
}

// fc2: inter[8192][5632] @ w2t^T -> out fp32
__global__ __launch_bounds__(256) void k_fc2n(const unsigned short* __restrict__ A,
                                              const unsigned short* __restrict__ BT,
                                              float* __restrict__ out) {
    __shared__ unsigned short As[128 * 64];
    __shared__ unsigned short Bs[128 * 64];
    const int bid = blockIdx.x;            // 1024 = 8 XCD * 128
    const int e   = bid & 7;
    const int idx = bid >> 3;              // 0..127
    const int mt  = idx & 7;               // mt innermost
    const int nt  = idx >> 3;              // 0..15
    const int t = threadIdx.x, lane = t & 63, w = t >> 6;
    const int m0 = e * TOK + mt * 128;
    const int n0 = nt * 128;
    const unsigned short* Ab = A + (size_t)m0 * INTER;
    const unsigned short* Bb = BT + (size_t)e * HID * INTER + (size_t)n0 * INTER;

    f32x4 acc[4][4];
#pragma unroll
    for (int i = 0; i < 4; ++i)
#pragma unroll
        for (int j = 0; j < 4; ++j) acc[i][j] = f32x4{0.f, 0.f, 0.f, 0.f};

    const int srow = lane >> 3;
    const int scol = (lane & 7) * 8;

    for (int k0 = 0; k0 < INTER; k0 += 64) {
#pragma unroll
        for (int i = 0; i < 4; ++i) {
            int j   = w * 4 + i;
            int row = j * 8 + srow;
            gload_lds16(Ab + (size_t)row * INTER + k0 + scol, (void*)(As + j * 512));
            gload_lds16(Bb + (size_t)row * INTER + k0 + scol, (void*)(Bs + j * 512));
        }
        __syncthreads();
        const int wr = (w >> 1) * 64, wc = (w & 1) * 64;
#pragma unroll
        for (int kk = 0; kk < 2; ++kk) {
            const int kb = kk * 32 + ((lane >> 4) << 3);
            bf16x8 a[4], b[4];
#pragma unroll
            for (int mf = 0; mf < 4; ++mf)
                a[mf] = *reinterpret_cast<const bf16x8*>(As + (wr + mf * 16 + (lane & 15)) * 64 + kb);
#pragma unroll
            for (int nf = 0; nf < 4; ++nf)
                b[nf] = *reinterpret_cast<const bf16x8*>(Bs + (wc + nf * 16 + (lane & 15)) * 64 + kb);
#pragma unroll
            for (int mf = 0; mf < 4; ++mf)
#pragma unroll
                for (int nf = 0; nf < 4; ++nf)
                    acc[mf][nf] = MFMA_BF16(a[mf], b[nf], acc[mf][nf]);
        }
        __syncthreads();
    }

    const int wr = (w >> 1) * 64, wc = (w & 1) * 64;
    const int cl = lane & 15;
#pragma unroll
    for (int mf = 0; mf < 4; ++mf)
#pragma unroll
        for (int nf = 0; nf < 4; ++nf)
#pragma unroll
            for (int r = 0; r < 4; ++r) {
                int row = m0 + wr + mf * 16 + ((lane >> 4) << 2) + r;
                int col = n0 + wc + nf * 16 + cl;
                out[(size_t)row * HID + col] = acc[mf][nf][r];
            }
}

// ---------------- fallback (round-1 kernels, need only 92 MB ws) ----------------

#define BM  128
#define BK  64
#define LDK 72

__global__ __launch_bounds__(256) void k_fc1_glu_fb(
    const float* __restrict__ X, const float* __restrict__ W1,
    unsigned short* __restrict__ inter)
{
    __shared__ unsigned short As[BM][LDK];
    __shared__ unsigned short Bs[128][LDK];
    const int bid = blockIdx.x;
    const int nt  = bid % (INTER / 64);
    const int mt  = (bid / (INTER / 64)) % (TOK / BM);
    const int e   = bid / ((INTER / 64) * (TOK / BM));
    const int t = threadIdx.x, lane = t & 63, w = t >> 6;
    const int m0 = mt * BM;
    const int rowbase = e * TOK + m0;
    f32x4 acc[2][8];
#pragma unroll
    for (int i = 0; i < 2; ++i)
#pragma unroll
        for (int jj = 0; jj < 8; ++jj) acc[i][jj] = f32x4{0.f, 0.f, 0.f, 0.f};
    const int jcol = t & 127;
    const int hf   = t >> 7;
    const int gcol = (jcol < 64) ? (nt * 64 + jcol) : (INTER + nt * 64 + (jcol - 64));
    const float* w1e = W1 + (size_t)e * HID * I2;
    for (int k0 = 0; k0 < HID; k0 += BK) {
#pragma unroll
        for (int it = 0; it < 8; ++it) {
            int lin = it * 256 + t;
            int r   = lin >> 4;
            int kq  = (lin & 15) << 2;
            const float4 v = *reinterpret_cast<const float4*>(
                X + (size_t)(rowbase + r) * HID + k0 + kq);
            ushort4 o;
            o.x = f2bf(v.x); o.y = f2bf(v.y); o.z = f2bf(v.z); o.w = f2bf(v.w);
            *reinterpret_cast<ushort4*>(&As[r][kq]) = o;
        }
#pragma unroll
        for (int it = 0; it < 8; ++it) {
            int kq = hf * 4 + it * 8;
            const float* p = w1e + (size_t)(k0 + kq) * I2 + gcol;
            float v0 = p[0], v1 = p[I2], v2 = p[2 * I2], v3 = p[3 * I2];
            ushort4 o;
            o.x = f2bf(v0); o.y = f2bf(v1); o.z = f2bf(v2); o.w = f2bf(v3);
            *reinterpret_cast<ushort4*>(&Bs[jcol][kq]) = o;
        }
        __syncthreads();
#pragma unroll
        for (int kk = 0; kk < 2; ++kk) {
            const int kb = kk * 32 + ((lane >> 4) << 3);
            bf16x8 a0 = *reinterpret_cast<const bf16x8*>(&As[w * 32 + (lane & 15)][kb]);
            bf16x8 a1 = *reinterpret_cast<const bf16x8*>(&As[w * 32 + 16 + (lane & 15)][kb]);
#pragma unroll
            for (int nf = 0; nf < 8; ++nf) {
                bf16x8 b = *reinterpret_cast<const bf16x8*>(&Bs[nf * 16 + (lane & 15)][kb]);
                acc[0][nf] = MFMA_BF16(a0, b, acc[0][nf]);
                acc[1][nf] = MFMA_BF16(a1, b, acc[1][nf]);
            }
        }
        __syncthreads();
    }
    const int rl0 = w * 32 + ((lane >> 4) << 2);
    const int cl  = lane & 15;
#pragma unroll
    for (int mf = 0; mf < 2; ++mf)
#pragma unroll
        for (int nfa = 0; nfa < 4; ++nfa) {
            f32x4 va = acc[mf][nfa];
            f32x4 vb = acc[mf][nfa + 4];
#pragma unroll
            for (int r = 0; r < 4; ++r) {
                float a = va[r], b = vb[r];
                float s = a / (1.f + __expf(-a)) * b;
                int row = rowbase + rl0 + mf * 16 + r;
                int col = nt * 64 + nfa * 16 + cl;
                inter[(size_t)row * INTER + col] = f2bf(s);
            }
        }
}

__global__ __launch_bounds__(256) void k_fc2_fb(
    const unsigned short* __restrict__ inter, const float* __restrict__ W2,
    float* __restrict__ out)
{
    __shared__ unsigned short As[BM][LDK];
    __shared__ unsigned short Bs[128][LDK];
    const int bid = blockIdx.x;
    const int nt  = bid % (HID / 128);
    const int mt  = (bid / (HID / 128)) % (TOK / BM);
    const int e   = bid / ((HID / 128) * (TOK / BM));
    const int t = threadIdx.x, lane = t & 63, w = t >> 6;
    const int m0 = mt * BM;
    const int rowbase = e * TOK + m0;
    f32x4 acc[2][8];
#pragma unroll
    for (int i = 0; i < 2; ++i)
#pragma unroll
        for (int jj = 0; jj < 8; ++jj) acc[i][jj] = f32x4{0.f, 0.f, 0.f, 0.f};
    const int jcol = t & 127;
    const int hf   = t >> 7;
    const int gcol = nt * 128 + jcol;
    const float* w2e = W2 + (size_t)e * INTER * HID;
    for (int k0 = 0; k0 < INTER; k0 += BK) {
#pragma unroll
        for (int it = 0; it < 4; ++it) {
            int lin = it * 256 + t;
            int r   = lin >> 3;
            int kq  = (lin & 7) << 3;
            uint4 v = *reinterpret_cast<const uint4*>(
                inter + (size_t)(rowbase + r) * INTER + k0 + kq);
            *reinterpret_cast<uint4*>(&As[r][kq]) = v;
        }
#pragma unroll
        for (int it = 0; it < 8; ++it) {
            int kq = hf * 4 + it * 8;
            const float* p = w2e + (size_t)(k0 + kq) * HID + gcol;
            float v0 = p[0], v1 = p[HID], v2 = p[2 * HID], v3 = p[3 * HID];
            ushort4 o;
            o.x = f2bf(v0); o.y = f2bf(v1); o.z = f2bf(v2); o.w = f2bf(v3);
            *reinterpret_cast<ushort4*>(&Bs[jcol][kq]) = o;
        }
        __syncthreads();
#pragma unroll
        for (int kk = 0; kk < 2; ++kk) {
            const int kb = kk * 32 + ((lane >> 4) << 3);
            bf16x8 a0 = *reinterpret_cast<const bf16x8*>(&As[w * 32 + (lane & 15)][kb]);
            bf16x8 a1 = *reinterpret_cast<const bf16x8*>(&As[w * 32 + 16 + (lane & 15)][kb]);
#pragma unroll
            for (int nf = 0; nf < 8; ++nf) {
                bf16x8 b = *reinterpret_cast<const bf16x8*>(&Bs[nf * 16 + (lane & 15)][kb]);
                acc[0][nf] = MFMA_BF16(a0, b, acc[0][nf]);
                acc[1][nf] = MFMA_BF16(a1, b, acc[1][nf]);
            }
        }
        __syncthreads();
    }
    const int rl0 = w * 32 + ((lane >> 4) << 2);
    const int cl  = lane & 15;
#pragma unroll
    for (int mf = 0; mf < 2; ++mf)
#pragma unroll
        for (int nf = 0; nf < 8; ++nf) {
            f32x4 v = acc[mf][nf];
#pragma unroll
            for (int r = 0; r < 4; ++r) {
                int row = rowbase + rl0 + mf * 16 + r;
                int col = nt * 128 + nf * 16 + cl;
                out[(size_t)row * HID + col] = v[r];
            }
        }
}

// ---------------- launch ----------------

extern "C" void kernel_launch(void* const* d_in, const int* in_sizes, int n_in,
                              void* d_out, int out_size, void* d_ws, size_t ws_size,
                              hipStream_t stream) {
    const float* X  = (const float*)d_in[0];
    const float* W1 = (const float*)d_in[1];
    const float* W2 = (const float*)d_in[2];
    float* out = (float*)d_out;

    const size_t XB_B  = (size_t)EXPERTS * TOK * HID * 2;
    const size_t W1T_B = (size_t)EXPERTS * I2 * HID * 2;
    const size_t W2T_B = (size_t)EXPERTS * HID * INTER * 2;
    const size_t INT_B = (size_t)EXPERTS * TOK * INTER * 2;
    const size_t need  = XB_B + W1T_B + W2T_B + INT_B;

    dim3 blk(256);
    if (ws_size >= need) {
        unsigned short* Xb    = (unsigned short*)d_ws;
        unsigned short* w1t   = (unsigned short*)((char*)d_ws + XB_B);
        unsigned short* w2t   = (unsigned short*)((char*)d_ws + XB_B + W1T_B);
        unsigned short* inter = (unsigned short*)((char*)d_ws + XB_B + W1T_B + W2T_B);

        k_cvt_x <<<(EXPERTS * TOK * HID) / (256 * 8), blk, 0, stream>>>(X, Xb);
        k_cvt_w1<<<EXPERTS * (I2 / 64) * (HID / 64),  blk, 0, stream>>>(W1, w1t);
        k_cvt_w2<<<EXPERTS * (HID / 64) * (INTER / 64), blk, 0, stream>>>(W2, w2t);
        k_fc1   <<<EXPERTS * (TOK / 128) * (I2 / 128),  blk, 0, stream>>>(Xb, w1t, inter);
        k_fc2n  <<<EXPERTS * (TOK / 128) * (HID / 128), blk, 0, stream>>>(inter, w2t, out);
    } else {
        unsigned short* inter = (unsigned short*)d_ws;
        k_fc1_glu_fb<<<EXPERTS * (TOK / BM) * (INTER / 64), blk, 0, stream>>>(X, W1, inter);
        k_fc2_fb    <<<EXPERTS * (TOK / BM) * (HID / 128),  blk, 0, stream>>>(inter, W2, out);
    }
}

// Round 10
// 922.588 us; speedup vs baseline: 1.4259x; 1.3670x over previous
//
#include <hip/hip_runtime.h>
#include <hip/hip_bf16.h>

// GroupedMLP: E=8, T=1024, H=2048, I=5632
// Round 9: ring-3 GEMM. 256x128 tile, BK=64, 8 waves x 64x64 output,
// LDS = 3 x 48KB buffers. ONE vmcnt(6) + ONE barrier per K-tile; stage(t+2)
// issued right after the barrier (2-tile prefetch covers cold-HBM latency);
// r6's fine A-stream||MFMA cluster interleave kept; r4's proven ws swizzle
// (granule XOR by row&7) and mt-innermost XCD ordering kept.

#define EXPERTS 8
#define TOK     1024
#define HID     2048
#define INTER   5632
#define I2      (2 * INTER)

typedef __bf16 bf16x8 __attribute__((ext_vector_type(8)));
typedef float  f32x4  __attribute__((ext_vector_type(4)));

__device__ __forceinline__ unsigned short f2bf(float f) {
    union { float f; unsigned u; } v; v.f = f;
    unsigned r = v.u + 0x7FFFu + ((v.u >> 16) & 1u);   // RNE
    return (unsigned short)(r >> 16);
}

__device__ __forceinline__ void gload_lds16(const void* g, void* l) {
    __builtin_amdgcn_global_load_lds(
        (const __attribute__((address_space(1))) void*)g,
        (__attribute__((address_space(3))) void*)l, 16, 0, 0);
}

// swizzled fragment read: rows are 64 ushorts (128B); 16B-granule XOR by row&7
__device__ __forceinline__ bf16x8 ldfrag(const unsigned short* S, int R, int kb) {
    int off = R * 64 + (kb ^ ((R & 7) << 3));
    return *reinterpret_cast<const bf16x8*>(S + off);
}

// ---------------- converts (r4 versions: granule-XOR swizzled ws) ----------------

__global__ __launch_bounds__(256) void k_cvt_x(const float* __restrict__ X,
                                               unsigned short* __restrict__ Xb) {
    size_t base = ((size_t)blockIdx.x * 256 + threadIdx.x) * 8;
    int row = (int)(base >> 11);
    int k   = (int)(base & (HID - 1));
    int kp  = k ^ ((row & 7) << 3);
    float4 v0 = *reinterpret_cast<const float4*>(X + base);
    float4 v1 = *reinterpret_cast<const float4*>(X + base + 4);
    uint4 o;
    o.x = (unsigned)f2bf(v0.x) | ((unsigned)f2bf(v0.y) << 16);
    o.y = (unsigned)f2bf(v0.z) | ((unsigned)f2bf(v0.w) << 16);
    o.z = (unsigned)f2bf(v1.x) | ((unsigned)f2bf(v1.y) << 16);
    o.w = (unsigned)f2bf(v1.z) | ((unsigned)f2bf(v1.w) << 16);
    *reinterpret_cast<uint4*>(Xb + (size_t)row * HID + kp) = o;
}

__global__ __launch_bounds__(256) void k_cvt_w1(const float* __restrict__ W1,
                                                unsigned short* __restrict__ W1T) {
    __shared__ unsigned short lds[64][72];
    const int bid = blockIdx.x;
    const int hb = bid % (HID / 64);
    const int pb = (bid / (HID / 64)) % (I2 / 64);
    const int e  = bid / ((HID / 64) * (I2 / 64));
    const int h0 = hb * 64, p0 = pb * 64, n0 = p0 >> 1;
    const float* w1e = W1 + (size_t)e * HID * I2;
    const int t = threadIdx.x;
#pragma unroll
    for (int it = 0; it < 16; ++it) {
        int lin   = it * 256 + t;
        int n_off = lin & 31;
        int c     = (lin >> 5) & 1;
        int h_off = lin >> 6;
        float v = w1e[(size_t)(h0 + h_off) * I2 + c * INTER + n0 + n_off];
        lds[2 * n_off + c][h_off] = f2bf(v);
    }
    __syncthreads();
    unsigned short* o = W1T + (size_t)e * I2 * HID;
#pragma unroll
    for (int it = 0; it < 4; ++it) {
        int lin = it * 256 + t;
        int r   = lin >> 4;
        int co  = (lin & 15) * 4;
        int cop = co ^ ((r & 7) << 3);
        ushort4 v = *reinterpret_cast<ushort4*>(&lds[r][co]);
        *reinterpret_cast<ushort4*>(o + (size_t)(p0 + r) * HID + h0 + cop) = v;
    }
}

__global__ __launch_bounds__(256) void k_cvt_w2(const float* __restrict__ W2,
                                                unsigned short* __restrict__ W2T) {
    __shared__ unsigned short lds[64][72];
    const int bid = blockIdx.x;
    const int ib = bid % (INTER / 64);
    const int hb = (bid / (INTER / 64)) % (HID / 64);
    const int e  = bid / ((INTER / 64) * (HID / 64));
    const int i0 = ib * 64, h0 = hb * 64;
    const float* w2e = W2 + (size_t)e * INTER * HID;
    const int t = threadIdx.x;
#pragma unroll
    for (int it = 0; it < 16; ++it) {
        int lin   = it * 256 + t;
        int h_off = lin & 63;
        int i_off = lin >> 6;
        float v = w2e[(size_t)(i0 + i_off) * HID + h0 + h_off];
        lds[h_off][i_off] = f2bf(v);
    }
    __syncthreads();
    unsigned short* o = W2T + (size_t)e * HID * INTER;
#pragma unroll
    for (int it = 0; it < 4; ++it) {
        int lin = it * 256 + t;
        int r   = lin >> 4;
        int co  = (lin & 15) * 4;
        int cop = co ^ ((r & 7) << 3);
        ushort4 v = *reinterpret_cast<ushort4*>(&lds[r][co]);
        *reinterpret_cast<ushort4*>(o + (size_t)(h0 + r) * INTER + i0 + cop) = v;
    }
}

// ---------------- ring-3 GEMM core: 256x128 tile, BK=64, 8 waves ----------------
// Buffer (48KB = 24576 ushorts): A [256][64] at 0, B [128][64] at +16384.
// Stage: 6 gload_lds16/thread (A 4 + B 2), linear dest.

__device__ __forceinline__ void stage48(const unsigned short* Ab, const unsigned short* Bb,
                                        int ktot, int k0, unsigned short* buf, int t) {
#pragma unroll
    for (int j = 0; j < 4; ++j) {
        int lin = j * 512 + t;
        gload_lds16(Ab + (size_t)(lin >> 3) * ktot + k0 + (lin & 7) * 8, buf + lin * 8);
    }
#pragma unroll
    for (int j = 0; j < 2; ++j) {
        int lin = j * 512 + t;
        gload_lds16(Bb + (size_t)(lin >> 3) * ktot + k0 + (lin & 7) * 8, buf + 16384 + lin * 8);
    }
}

#define MFMA_BF16(a, b, c) __builtin_amdgcn_mfma_f32_16x16x32_bf16(a, b, c, 0, 0, 0)

__device__ __forceinline__ void gemm_ring3(const unsigned short* Ab, const unsigned short* Bb,
                                           int ktot, int nkt, f32x4 (&acc)[4][4],
                                           unsigned short* lds, int t, int lane,
                                           int wr, int wc) {
    const int cl  = lane & 15;
    const int kb0 = (lane >> 4) << 3;

    // prologue: stage tiles 0 and 1 (12 loads outstanding)
    stage48(Ab, Bb, ktot, 0,  lds,         t);
    stage48(Ab, Bb, ktot, 64, lds + 24576, t);

    int c_cur = 0, c_n2 = 2;
    for (int kt = 0; kt < nkt; ++kt) {
        // own stage(kt) done (newest 6 = stage(kt+1) may stay in flight)
        if (kt + 1 < nkt) { asm volatile("s_waitcnt vmcnt(6)" ::: "memory"); }
        else              { asm volatile("s_waitcnt vmcnt(0)" ::: "memory"); }
        __builtin_amdgcn_s_barrier();   // collective: buf[c_cur] landed; buf[c_n2] free
        asm volatile("" ::: "memory");

        unsigned short* Ac = lds + c_cur * 24576;
        unsigned short* Bc = Ac + 16384;

        if (kt + 2 < nkt)
            stage48(Ab, Bb, ktot, (kt + 2) * 64, lds + c_n2 * 24576, t);

        bf16x8 a[2][2], b[4][2];
#pragma unroll
        for (int k = 0; k < 2; ++k)
            a[0][k] = ldfrag(Ac, wr + cl, k * 32 + kb0);
#pragma unroll
        for (int n = 0; n < 4; ++n)
#pragma unroll
            for (int k = 0; k < 2; ++k)
                b[n][k] = ldfrag(Bc, wc + n * 16 + cl, k * 32 + kb0);

#pragma unroll
        for (int m = 0; m < 4; ++m) {
            if (m < 3) {
#pragma unroll
                for (int k = 0; k < 2; ++k)
                    a[(m + 1) & 1][k] = ldfrag(Ac, wr + (m + 1) * 16 + cl, k * 32 + kb0);
            }
            __builtin_amdgcn_s_setprio(1);
#pragma unroll
            for (int n = 0; n < 4; ++n)
#pragma unroll
                for (int k = 0; k < 2; ++k)
                    acc[m][n] = MFMA_BF16(a[m & 1][k], b[n][k], acc[m][n]);
            __builtin_amdgcn_s_setprio(0);
        }

        c_cur = (c_cur == 2) ? 0 : c_cur + 1;
        c_n2  = (c_n2  == 2) ? 0 : c_n2  + 1;
    }
}

// fc1: Xb @ w1t^T -> inter bf16 (GLU fused, swizzled store)
__global__ __launch_bounds__(512, 2) void k_fc1_r3(const unsigned short* __restrict__ Xb,
                                                   const unsigned short* __restrict__ W1T,
                                                   unsigned short* __restrict__ inter) {
    extern __shared__ unsigned short lds[];
    const int bid = blockIdx.x;                // 2816 = 8 XCD * (4 mt * 88 nt)
    const int e   = bid & 7;
    const int idx = bid >> 3;
    const int mt  = idx & 3;                   // mt innermost: B-panel shared
    const int nt  = idx >> 2;                  // 0..87
    const int t = threadIdx.x, lane = t & 63, w = t >> 6;
    const int wr = (w >> 1) * 64;              // 4 M-groups
    const int wc = (w & 1) * 64;               // 2 N-groups
    const int m0 = e * TOK + mt * 256;
    const int n0 = nt * 128;                   // pc-space
    const unsigned short* Ab = Xb  + (size_t)m0 * HID;
    const unsigned short* Bb = W1T + (size_t)e * I2 * HID + (size_t)n0 * HID;

    f32x4 acc[4][4];
#pragma unroll
    for (int i = 0; i < 4; ++i)
#pragma unroll
        for (int j = 0; j < 4; ++j) acc[i][j] = f32x4{0.f, 0.f, 0.f, 0.f};

    gemm_ring3(Ab, Bb, HID, HID / 64, acc, lds, t, lane, wr, wc);

    const int cl = lane & 15;
    const int r0 = (lane >> 4) << 2;
#pragma unroll
    for (int mf = 0; mf < 4; ++mf)
#pragma unroll
        for (int nf = 0; nf < 4; ++nf)
#pragma unroll
            for (int r = 0; r < 4; ++r) {
                float v  = acc[mf][nf][r];
                float pv = __shfl_xor(v, 1);
                if ((lane & 1) == 0) {
                    float s = v / (1.f + __expf(-v)) * pv;
                    int row = m0 + wr + mf * 16 + r0 + r;
                    int pc  = n0 + wc + nf * 16 + cl;
                    int c   = pc >> 1;
                    int c2  = (c & ~63) | ((c & 63) ^ ((row & 7) << 3));
                    inter[(size_t)row * INTER + c2] = f2bf(s);
                }
            }
}

// fc2: inter @ w2t^T -> out fp32
__global__ __launch_bounds__(512, 2) void k_fc2_r3(const unsigned short* __restrict__ A,
                                                   const unsigned short* __restrict__ W2T,
                                                   float* __restrict__ out) {
    extern __shared__ unsigned short lds[];
    const int bid = blockIdx.x;                // 512 = 8 XCD * (4 mt * 16 nt)
    const int e   = bid & 7;
    const int idx = bid >> 3;
    const int mt  = idx & 3;
    const int nt  = idx >> 2;                  // 0..15
    const int t = threadIdx.x, lane = t & 63, w = t >> 6;
    const int wr = (w >> 1) * 64;
    const int wc = (w & 1) * 64;
    const int m0 = e * TOK + mt * 256;
    const int n0 = nt * 128;
    const unsigned short* Ab = A   + (size_t)m0 * INTER;
    const unsigned short* Bb = W2T + (size_t)e * HID * INTER + (size_t)n0 * INTER;

    f32x4 acc[4][4];
#pragma unroll
    for (int i = 0; i < 4; ++i)
#pragma unroll
        for (int j = 0; j < 4; ++j) acc[i][j] = f32x4{0.f, 0.f, 0.f, 0.f};

    gemm_ring3(Ab, Bb, INTER, INTER / 64, acc, lds, t, lane, wr, wc);

    const int cl = lane & 15;
    const int r0 = (lane >> 4) << 2;
#pragma unroll
    for (int mf = 0; mf < 4; ++mf)
#pragma unroll
        for (int nf = 0; nf < 4; ++nf)
#pragma unroll
            for (int r = 0; r < 4; ++r) {
                int row = m0 + wr + mf * 16 + r0 + r;
                int col = n0 + wc + nf * 16 + cl;
                out[(size_t)row * HID + col] = acc[mf][nf][r];
            }
}

// ---------------- fallback (round-1 kernels, need only 92 MB ws) ----------------

#define BM  128
#define BK  64
#define LDK 72

__global__ __launch_bounds__(256) void k_fc1_glu_fb(
    const float* __restrict__ X, const float* __restrict__ W1,
    unsigned short* __restrict__ inter)
{
    __shared__ unsigned short As[BM][LDK];
    __shared__ unsigned short Bs[128][LDK];
    const int bid = blockIdx.x;
    const int nt  = bid % (INTER / 64);
    const int mt  = (bid / (INTER / 64)) % (TOK / BM);
    const int e   = bid / ((INTER / 64) * (TOK / BM));
    const int t = threadIdx.x, lane = t & 63, w = t >> 6;
    const int m0 = mt * BM;
    const int rowbase = e * TOK + m0;
    f32x4 acc[2][8];
#pragma unroll
    for (int i = 0; i < 2; ++i)
#pragma unroll
        for (int jj = 0; jj < 8; ++jj) acc[i][jj] = f32x4{0.f, 0.f, 0.f, 0.f};
    const int jcol = t & 127;
    const int hf   = t >> 7;
    const int gcol = (jcol < 64) ? (nt * 64 + jcol) : (INTER + nt * 64 + (jcol - 64));
    const float* w1e = W1 + (size_t)e * HID * I2;
    for (int k0 = 0; k0 < HID; k0 += BK) {
#pragma unroll
        for (int it = 0; it < 8; ++it) {
            int lin = it * 256 + t;
            int r   = lin >> 4;
            int kq  = (lin & 15) << 2;
            const float4 v = *reinterpret_cast<const float4*>(
                X + (size_t)(rowbase + r) * HID + k0 + kq);
            ushort4 o;
            o.x = f2bf(v.x); o.y = f2bf(v.y); o.z = f2bf(v.z); o.w = f2bf(v.w);
            *reinterpret_cast<ushort4*>(&As[r][kq]) = o;
        }
#pragma unroll
        for (int it = 0; it < 8; ++it) {
            int kq = hf * 4 + it * 8;
            const float* p = w1e + (size_t)(k0 + kq) * I2 + gcol;
            float v0 = p[0], v1 = p[I2], v2 = p[2 * I2], v3 = p[3 * I2];
            ushort4 o;
            o.x = f2bf(v0); o.y = f2bf(v1); o.z = f2bf(v2); o.w = f2bf(v3);
            *reinterpret_cast<ushort4*>(&Bs[jcol][kq]) = o;
        }
        __syncthreads();
#pragma unroll
        for (int kk = 0; kk < 2; ++kk) {
            const int kb = kk * 32 + ((lane >> 4) << 3);
            bf16x8 a0 = *reinterpret_cast<const bf16x8*>(&As[w * 32 + (lane & 15)][kb]);
            bf16x8 a1 = *reinterpret_cast<const bf16x8*>(&As[w * 32 + 16 + (lane & 15)][kb]);
#pragma unroll
            for (int nf = 0; nf < 8; ++nf) {
                bf16x8 b = *reinterpret_cast<const bf16x8*>(&Bs[nf * 16 + (lane & 15)][kb]);
                acc[0][nf] = MFMA_BF16(a0, b, acc[0][nf]);
                acc[1][nf] = MFMA_BF16(a1, b, acc[1][nf]);
            }
        }
        __syncthreads();
    }
    const int rl0 = w * 32 + ((lane >> 4) << 2);
    const int cl  = lane & 15;
#pragma unroll
    for (int mf = 0; mf < 2; ++mf)
#pragma unroll
        for (int nfa = 0; nfa < 4; ++nfa) {
            f32x4 va = acc[mf][nfa];
            f32x4 vb = acc[mf][nfa + 4];
#pragma unroll
            for (int r = 0; r < 4; ++r) {
                float a = va[r], b = vb[r];
                float s = a / (1.f + __expf(-a)) * b;
                int row = rowbase + rl0 + mf * 16 + r;
                int col = nt * 64 + nfa * 16 + cl;
                inter[(size_t)row * INTER + col] = f2bf(s);
            }
        }
}

__global__ __launch_bounds__(256) void k_fc2_fb(
    const unsigned short* __restrict__ inter, const float* __restrict__ W2,
    float* __restrict__ out)
{
    __shared__ unsigned short As[BM][LDK];
    __shared__ unsigned short Bs[128][LDK];
    const int bid = blockIdx.x;
    const int nt  = bid % (HID / 128);
    const int mt  = (bid / (HID / 128)) % (TOK / BM);
    const int e   = bid / ((HID / 128) * (TOK / BM));
    const int t = threadIdx.x, lane = t & 63, w = t >> 6;
    const int m0 = mt * BM;
    const int rowbase = e * TOK + m0;
    f32x4 acc[2][8];
#pragma unroll
    for (int i = 0; i < 2; ++i)
#pragma unroll
        for (int jj = 0; jj < 8; ++jj) acc[i][jj] = f32x4{0.f, 0.f, 0.f, 0.f};
    const int jcol = t & 127;
    const int hf   = t >> 7;
    const int gcol = nt * 128 + jcol;
    const float* w2e = W2 + (size_t)e * INTER * HID;
    for (int k0 = 0; k0 < INTER; k0 += BK) {
#pragma unroll
        for (int it = 0; it < 4; ++it) {
            int lin = it * 256 + t;
            int r   = lin >> 3;
            int kq  = (lin & 7) << 3;
            uint4 v = *reinterpret_cast<const uint4*>(
                inter + (size_t)(rowbase + r) * INTER + k0 + kq);
            *reinterpret_cast<uint4*>(&As[r][kq]) = v;
        }
#pragma unroll
        for (int it = 0; it < 8; ++it) {
            int kq = hf * 4 + it * 8;
            const float* p = w2e + (size_t)(k0 + kq) * HID + gcol;
            float v0 = p[0], v1 = p[HID], v2 = p[2 * HID], v3 = p[3 * HID];
            ushort4 o;
            o.x = f2bf(v0); o.y = f2bf(v1); o.z = f2bf(v2); o.w = f2bf(v3);
            *reinterpret_cast<ushort4*>(&Bs[jcol][kq]) = o;
        }
        __syncthreads();
#pragma unroll
        for (int kk = 0; kk < 2; ++kk) {
            const int kb = kk * 32 + ((lane >> 4) << 3);
            bf16x8 a0 = *reinterpret_cast<const bf16x8*>(&As[w * 32 + (lane & 15)][kb]);
            bf16x8 a1 = *reinterpret_cast<const bf16x8*>(&As[w * 32 + 16 + (lane & 15)][kb]);
#pragma unroll
            for (int nf = 0; nf < 8; ++nf) {
                bf16x8 b = *reinterpret_cast<const bf16x8*>(&Bs[nf * 16 + (lane & 15)][kb]);
                acc[0][nf] = MFMA_BF16(a0, b, acc[0][nf]);
                acc[1][nf] = MFMA_BF16(a1, b, acc[1][nf]);
            }
        }
        __syncthreads();
    }
    const int rl0 = w * 32 + ((lane >> 4) << 2);
    const int cl  = lane & 15;
#pragma unroll
    for (int mf = 0; mf < 2; ++mf)
#pragma unroll
        for (int nf = 0; nf < 8; ++nf) {
            f32x4 v = acc[mf][nf];
#pragma unroll
            for (int r = 0; r < 4; ++r) {
                int row = rowbase + rl0 + mf * 16 + r;
                int col = nt * 128 + nf * 16 + cl;
                out[(size_t)row * HID + col] = v[r];
            }
        }
}

// ---------------- launch ----------------

extern "C" void kernel_launch(void* const* d_in, const int* in_sizes, int n_in,
                              void* d_out, int out_size, void* d_ws, size_t ws_size,
                              hipStream_t stream) {
    const float* X  = (const float*)d_in[0];
    const float* W1 = (const float*)d_in[1];
    const float* W2 = (const float*)d_in[2];
    float* out = (float*)d_out;

    const size_t XB_B  = (size_t)EXPERTS * TOK * HID * 2;
    const size_t W1T_B = (size_t)EXPERTS * I2 * HID * 2;
    const size_t W2T_B = (size_t)EXPERTS * HID * INTER * 2;
    const size_t INT_B = (size_t)EXPERTS * TOK * INTER * 2;
    const size_t need  = XB_B + W1T_B + W2T_B + INT_B;

    if (ws_size >= need) {
        unsigned short* Xb    = (unsigned short*)d_ws;
        unsigned short* w1t   = (unsigned short*)((char*)d_ws + XB_B);
        unsigned short* w2t   = (unsigned short*)((char*)d_ws + XB_B + W1T_B);
        unsigned short* inter = (unsigned short*)((char*)d_ws + XB_B + W1T_B + W2T_B);

        hipFuncSetAttribute((const void*)k_fc1_r3,
            hipFuncAttributeMaxDynamicSharedMemorySize, 147456);
        hipFuncSetAttribute((const void*)k_fc2_r3,
            hipFuncAttributeMaxDynamicSharedMemorySize, 147456);

        dim3 b256(256), b512(512);
        k_cvt_x <<<(EXPERTS * TOK * HID) / (256 * 8), b256, 0, stream>>>(X, Xb);
        k_cvt_w1<<<EXPERTS * (I2 / 64) * (HID / 64),   b256, 0, stream>>>(W1, w1t);
        k_cvt_w2<<<EXPERTS * (HID / 64) * (INTER / 64), b256, 0, stream>>>(W2, w2t);
        k_fc1_r3<<<EXPERTS * 4 * (I2 / 128),  b512, 147456, stream>>>(Xb, w1t, inter);
        k_fc2_r3<<<EXPERTS * 4 * (HID / 128), b512, 147456, stream>>>(inter, w2t, out);
    } else {
        unsigned short* inter = (unsigned short*)d_ws;
        dim3 b256(256);
        k_fc1_glu_fb<<<EXPERTS * (TOK / BM) * (INTER / 64), b256, 0, stream>>>(X, W1, inter);
        k_fc2_fb    <<<EXPERTS * (TOK / BM) * (HID / 128),  b256, 0, stream>>>(inter, W2, out);
    }
}

// Round 11
// 911.561 us; speedup vs baseline: 1.4431x; 1.0121x over previous
//
#include <hip/hip_runtime.h>
#include <hip/hip_bf16.h>

// GroupedMLP: E=8, T=1024, H=2048, I=5632
// Round 10: ring-3 schedule kept (1 barrier + counted vmcnt per K-tile,
// stage(t+2) after barrier), re-geometried for occupancy: 256x256 tile,
// BK=32, 1024 threads = 16 waves of 64x64, ring-3 buffers 3x32KB = 96KB,
// VGPR ~24 + acc-in-AGPR 64 <= 128 total -> 16 waves/CU (4/SIMD) so the
// LDS-read pipe (1506 cyc/tile/CU) and MFMA pipe (1243) overlap instead of
// serializing (r9 measured their sum). Swizzle re-derived for the 32-elem
// tile window: granule XOR (row>>1)&3 on element bits 3-4 (2-way = free).

#define EXPERTS 8
#define TOK     1024
#define HID     2048
#define INTER   5632
#define I2      (2 * INTER)

typedef __bf16 bf16x8 __attribute__((ext_vector_type(8)));
typedef float  f32x4  __attribute__((ext_vector_type(4)));

#define G2(row) ((((row) >> 1) & 3) << 3)   // element-index XOR, bits 3-4

__device__ __forceinline__ unsigned short f2bf(float f) {
    union { float f; unsigned u; } v; v.f = f;
    unsigned r = v.u + 0x7FFFu + ((v.u >> 16) & 1u);   // RNE
    return (unsigned short)(r >> 16);
}

__device__ __forceinline__ void gload_lds16(const void* g, void* l) {
    __builtin_amdgcn_global_load_lds(
        (const __attribute__((address_space(1))) void*)g,
        (__attribute__((address_space(3))) void*)l, 16, 0, 0);
}

// fragment read from a [rows][32] bf16 tile, swizzled by G2(row)
__device__ __forceinline__ bf16x8 ldfrag(const unsigned short* S, int R, int kb) {
    int off = R * 32 + (kb ^ G2(R));
    return *reinterpret_cast<const bf16x8*>(S + off);
}

// ---------------- converts (write G2-swizzled ws layouts) ----------------

__global__ __launch_bounds__(256) void k_cvt_x(const float* __restrict__ X,
                                               unsigned short* __restrict__ Xb) {
    size_t base = ((size_t)blockIdx.x * 256 + threadIdx.x) * 8;
    int row = (int)(base >> 11);
    int k   = (int)(base & (HID - 1));
    int kp  = k ^ G2(row);
    float4 v0 = *reinterpret_cast<const float4*>(X + base);
    float4 v1 = *reinterpret_cast<const float4*>(X + base + 4);
    uint4 o;
    o.x = (unsigned)f2bf(v0.x) | ((unsigned)f2bf(v0.y) << 16);
    o.y = (unsigned)f2bf(v0.z) | ((unsigned)f2bf(v0.w) << 16);
    o.z = (unsigned)f2bf(v1.x) | ((unsigned)f2bf(v1.y) << 16);
    o.w = (unsigned)f2bf(v1.z) | ((unsigned)f2bf(v1.w) << 16);
    *reinterpret_cast<uint4*>(Xb + (size_t)row * HID + kp) = o;
}

__global__ __launch_bounds__(256) void k_cvt_w1(const float* __restrict__ W1,
                                                unsigned short* __restrict__ W1T) {
    __shared__ unsigned short lds[64][72];
    const int bid = blockIdx.x;
    const int hb = bid % (HID / 64);
    const int pb = (bid / (HID / 64)) % (I2 / 64);
    const int e  = bid / ((HID / 64) * (I2 / 64));
    const int h0 = hb * 64, p0 = pb * 64, n0 = p0 >> 1;
    const float* w1e = W1 + (size_t)e * HID * I2;
    const int t = threadIdx.x;
#pragma unroll
    for (int it = 0; it < 16; ++it) {
        int lin   = it * 256 + t;
        int n_off = lin & 31;
        int c     = (lin >> 5) & 1;
        int h_off = lin >> 6;
        float v = w1e[(size_t)(h0 + h_off) * I2 + c * INTER + n0 + n_off];
        lds[2 * n_off + c][h_off] = f2bf(v);
    }
    __syncthreads();
    unsigned short* o = W1T + (size_t)e * I2 * HID;
#pragma unroll
    for (int it = 0; it < 4; ++it) {
        int lin = it * 256 + t;
        int r   = lin >> 4;
        int co  = (lin & 15) * 4;
        int cop = co ^ G2(r);        // p0 is a multiple of 64 -> local r ok
        ushort4 v = *reinterpret_cast<ushort4*>(&lds[r][co]);
        *reinterpret_cast<ushort4*>(o + (size_t)(p0 + r) * HID + h0 + cop) = v;
    }
}

__global__ __launch_bounds__(256) void k_cvt_w2(const float* __restrict__ W2,
                                                unsigned short* __restrict__ W2T) {
    __shared__ unsigned short lds[64][72];
    const int bid = blockIdx.x;
    const int ib = bid % (INTER / 64);
    const int hb = (bid / (INTER / 64)) % (HID / 64);
    const int e  = bid / ((INTER / 64) * (HID / 64));
    const int i0 = ib * 64, h0 = hb * 64;
    const float* w2e = W2 + (size_t)e * INTER * HID;
    const int t = threadIdx.x;
#pragma unroll
    for (int it = 0; it < 16; ++it) {
        int lin   = it * 256 + t;
        int h_off = lin & 63;
        int i_off = lin >> 6;
        float v = w2e[(size_t)(i0 + i_off) * HID + h0 + h_off];
        lds[h_off][i_off] = f2bf(v);
    }
    __syncthreads();
    unsigned short* o = W2T + (size_t)e * HID * INTER;
#pragma unroll
    for (int it = 0; it < 4; ++it) {
        int lin = it * 256 + t;
        int r   = lin >> 4;
        int co  = (lin & 15) * 4;
        int cop = co ^ G2(r);
        ushort4 v = *reinterpret_cast<ushort4*>(&lds[r][co]);
        *reinterpret_cast<ushort4*>(o + (size_t)(h0 + r) * INTER + i0 + cop) = v;
    }
}

// ---------------- ring-3 GEMM core: 256x256 tile, BK=32, 16 waves ----------------
// Buffer (32KB = 16384 ushorts): A [256][32] at 0, B [256][32] at +8192.
// Stage: 1 A + 1 B gload_lds16 per thread (1024 threads), linear dest.

__device__ __forceinline__ void stage32(const unsigned short* Ab, const unsigned short* Bb,
                                        int ktot, int k0, unsigned short* buf, int t) {
    const int row = t >> 2;
    const int col = (t & 3) * 8;
    gload_lds16(Ab + (size_t)row * ktot + k0 + col, buf + t * 8);
    gload_lds16(Bb + (size_t)row * ktot + k0 + col, buf + 8192 + t * 8);
}

#define MFMA_BF16(a, b, c) __builtin_amdgcn_mfma_f32_16x16x32_bf16(a, b, c, 0, 0, 0)

__device__ __forceinline__ void gemm_ring3(const unsigned short* Ab, const unsigned short* Bb,
                                           int ktot, int nkt, f32x4 (&acc)[4][4],
                                           unsigned short* lds, int t, int lane,
                                           int wr, int wc) {
    const int cl  = lane & 15;
    const int kb0 = (lane >> 4) << 3;

    // prologue: stage tiles 0 and 1 (4 loads outstanding)
    stage32(Ab, Bb, ktot, 0,  lds,         t);
    stage32(Ab, Bb, ktot, 32, lds + 16384, t);

    int c_cur = 0, c_n2 = 2;
    for (int kt = 0; kt < nkt; ++kt) {
        if (kt + 1 < nkt) { asm volatile("s_waitcnt vmcnt(2)" ::: "memory"); }
        else              { asm volatile("s_waitcnt vmcnt(0)" ::: "memory"); }
        __builtin_amdgcn_s_barrier();   // buf[c_cur] landed everywhere; buf[c_n2] free
        asm volatile("" ::: "memory");

        unsigned short* Ac = lds + c_cur * 16384;
        unsigned short* Bc = Ac + 8192;

        if (kt + 2 < nkt)
            stage32(Ab, Bb, ktot, (kt + 2) * 32, lds + c_n2 * 16384, t);

        bf16x8 b[4], a[2];
#pragma unroll
        for (int n = 0; n < 4; ++n)
            b[n] = ldfrag(Bc, wc + n * 16 + cl, kb0);
        a[0] = ldfrag(Ac, wr + cl, kb0);

#pragma unroll
        for (int m = 0; m < 4; ++m) {
            if (m < 3)
                a[(m + 1) & 1] = ldfrag(Ac, wr + (m + 1) * 16 + cl, kb0);
            __builtin_amdgcn_s_setprio(1);
#pragma unroll
            for (int n = 0; n < 4; ++n)
                acc[m][n] = MFMA_BF16(a[m & 1], b[n], acc[m][n]);
            __builtin_amdgcn_s_setprio(0);
        }

        c_cur = (c_cur == 2) ? 0 : c_cur + 1;
        c_n2  = (c_n2  == 2) ? 0 : c_n2  + 1;
    }
}

// fc1: Xb @ w1t^T -> inter bf16 (GLU fused, G2-swizzled store)
__global__ __launch_bounds__(1024, 1) void k_fc1_r3(const unsigned short* __restrict__ Xb,
                                                    const unsigned short* __restrict__ W1T,
                                                    unsigned short* __restrict__ inter) {
    extern __shared__ unsigned short lds[];
    const int bid = blockIdx.x;                // 1408 = 8 XCD * (4 mt * 44 nt)
    const int e   = bid & 7;
    const int idx = bid >> 3;
    const int mt  = idx & 3;                   // mt innermost: B-panel shared
    const int nt  = idx >> 2;                  // 0..43
    const int t = threadIdx.x, lane = t & 63, w = t >> 6;
    const int wr = (w >> 2) * 64;              // 4x4 wave grid of 64x64
    const int wc = (w & 3) * 64;
    const int m0 = e * TOK + mt * 256;
    const int n0 = nt * 256;                   // pc-space
    const unsigned short* Ab = Xb  + (size_t)m0 * HID;
    const unsigned short* Bb = W1T + (size_t)e * I2 * HID + (size_t)n0 * HID;

    f32x4 acc[4][4];
#pragma unroll
    for (int i = 0; i < 4; ++i)
#pragma unroll
        for (int j = 0; j < 4; ++j) acc[i][j] = f32x4{0.f, 0.f, 0.f, 0.f};

    gemm_ring3(Ab, Bb, HID, HID / 32, acc, lds, t, lane, wr, wc);

    const int cl = lane & 15;
    const int r0 = (lane >> 4) << 2;
#pragma unroll
    for (int mf = 0; mf < 4; ++mf)
#pragma unroll
        for (int nf = 0; nf < 4; ++nf)
#pragma unroll
            for (int r = 0; r < 4; ++r) {
                float v  = acc[mf][nf][r];
                float pv = __shfl_xor(v, 1);
                if ((lane & 1) == 0) {
                    float s = v / (1.f + __expf(-v)) * pv;
                    int row = m0 + wr + mf * 16 + r0 + r;
                    int pc  = n0 + wc + nf * 16 + cl;
                    int c   = pc >> 1;
                    int c2  = (c & ~31) | ((c & 31) ^ G2(row));  // fc2-A swizzle
                    inter[(size_t)row * INTER + c2] = f2bf(s);
                }
            }
}

// fc2: inter @ w2t^T -> out fp32
__global__ __launch_bounds__(1024, 1) void k_fc2_r3(const unsigned short* __restrict__ A,
                                                    const unsigned short* __restrict__ W2T,
                                                    float* __restrict__ out) {
    extern __shared__ unsigned short lds[];
    const int bid = blockIdx.x;                // 256 = 8 XCD * (4 mt * 8 nt)
    const int e   = bid & 7;
    const int idx = bid >> 3;
    const int mt  = idx & 3;
    const int nt  = idx >> 2;                  // 0..7
    const int t = threadIdx.x, lane = t & 63, w = t >> 6;
    const int wr = (w >> 2) * 64;
    const int wc = (w & 3) * 64;
    const int m0 = e * TOK + mt * 256;
    const int n0 = nt * 256;
    const unsigned short* Ab = A   + (size_t)m0 * INTER;
    const unsigned short* Bb = W2T + (size_t)e * HID * INTER + (size_t)n0 * INTER;

    f32x4 acc[4][4];
#pragma unroll
    for (int i = 0; i < 4; ++i)
#pragma unroll
        for (int j = 0; j < 4; ++j) acc[i][j] = f32x4{0.f, 0.f, 0.f, 0.f};

    gemm_ring3(Ab, Bb, INTER, INTER / 32, acc, lds, t, lane, wr, wc);

    const int cl = lane & 15;
    const int r0 = (lane >> 4) << 2;
#pragma unroll
    for (int mf = 0; mf < 4; ++mf)
#pragma unroll
        for (int nf = 0; nf < 4; ++nf)
#pragma unroll
            for (int r = 0; r < 4; ++r) {
                int row = m0 + wr + mf * 16 + r0 + r;
                int col = n0 + wc + nf * 16 + cl;
                out[(size_t)row * HID + col] = acc[mf][nf][r];
            }
}

// ---------------- fallback (round-1 kernels, need only 92 MB ws) ----------------

#define BM  128
#define BK  64
#define LDK 72

__global__ __launch_bounds__(256) void k_fc1_glu_fb(
    const float* __restrict__ X, const float* __restrict__ W1,
    unsigned short* __restrict__ inter)
{
    __shared__ unsigned short As[BM][LDK];
    __shared__ unsigned short Bs[128][LDK];
    const int bid = blockIdx.x;
    const int nt  = bid % (INTER / 64);
    const int mt  = (bid / (INTER / 64)) % (TOK / BM);
    const int e   = bid / ((INTER / 64) * (TOK / BM));
    const int t = threadIdx.x, lane = t & 63, w = t >> 6;
    const int m0 = mt * BM;
    const int rowbase = e * TOK + m0;
    f32x4 acc[2][8];
#pragma unroll
    for (int i = 0; i < 2; ++i)
#pragma unroll
        for (int jj = 0; jj < 8; ++jj) acc[i][jj] = f32x4{0.f, 0.f, 0.f, 0.f};
    const int jcol = t & 127;
    const int hf   = t >> 7;
    const int gcol = (jcol < 64) ? (nt * 64 + jcol) : (INTER + nt * 64 + (jcol - 64));
    const float* w1e = W1 + (size_t)e * HID * I2;
    for (int k0 = 0; k0 < HID; k0 += BK) {
#pragma unroll
        for (int it = 0; it < 8; ++it) {
            int lin = it * 256 + t;
            int r   = lin >> 4;
            int kq  = (lin & 15) << 2;
            const float4 v = *reinterpret_cast<const float4*>(
                X + (size_t)(rowbase + r) * HID + k0 + kq);
            ushort4 o;
            o.x = f2bf(v.x); o.y = f2bf(v.y); o.z = f2bf(v.z); o.w = f2bf(v.w);
            *reinterpret_cast<ushort4*>(&As[r][kq]) = o;
        }
#pragma unroll
        for (int it = 0; it < 8; ++it) {
            int kq = hf * 4 + it * 8;
            const float* p = w1e + (size_t)(k0 + kq) * I2 + gcol;
            float v0 = p[0], v1 = p[I2], v2 = p[2 * I2], v3 = p[3 * I2];
            ushort4 o;
            o.x = f2bf(v0); o.y = f2bf(v1); o.z = f2bf(v2); o.w = f2bf(v3);
            *reinterpret_cast<ushort4*>(&Bs[jcol][kq]) = o;
        }
        __syncthreads();
#pragma unroll
        for (int kk = 0; kk < 2; ++kk) {
            const int kb = kk * 32 + ((lane >> 4) << 3);
            bf16x8 a0 = *reinterpret_cast<const bf16x8*>(&As[w * 32 + (lane & 15)][kb]);
            bf16x8 a1 = *reinterpret_cast<const bf16x8*>(&As[w * 32 + 16 + (lane & 15)][kb]);
#pragma unroll
            for (int nf = 0; nf < 8; ++nf) {
                bf16x8 b = *reinterpret_cast<const bf16x8*>(&Bs[nf * 16 + (lane & 15)][kb]);
                acc[0][nf] = MFMA_BF16(a0, b, acc[0][nf]);
                acc[1][nf] = MFMA_BF16(a1, b, acc[1][nf]);
            }
        }
        __syncthreads();
    }
    const int rl0 = w * 32 + ((lane >> 4) << 2);
    const int cl  = lane & 15;
#pragma unroll
    for (int mf = 0; mf < 2; ++mf)
#pragma unroll
        for (int nfa = 0; nfa < 4; ++nfa) {
            f32x4 va = acc[mf][nfa];
            f32x4 vb = acc[mf][nfa + 4];
#pragma unroll
            for (int r = 0; r < 4; ++r) {
                float a = va[r], b = vb[r];
                float s = a / (1.f + __expf(-a)) * b;
                int row = rowbase + rl0 + mf * 16 + r;
                int col = nt * 64 + nfa * 16 + cl;
                inter[(size_t)row * INTER + col] = f2bf(s);
            }
        }
}

__global__ __launch_bounds__(256) void k_fc2_fb(
    const unsigned short* __restrict__ inter, const float* __restrict__ W2,
    float* __restrict__ out)
{
    __shared__ unsigned short As[BM][LDK];
    __shared__ unsigned short Bs[128][LDK];
    const int bid = blockIdx.x;
    const int nt  = bid % (HID / 128);
    const int mt  = (bid / (HID / 128)) % (TOK / BM);
    const int e   = bid / ((HID / 128) * (TOK / BM));
    const int t = threadIdx.x, lane = t & 63, w = t >> 6;
    const int m0 = mt * BM;
    const int rowbase = e * TOK + m0;
    f32x4 acc[2][8];
#pragma unroll
    for (int i = 0; i < 2; ++i)
#pragma unroll
        for (int jj = 0; jj < 8; ++jj) acc[i][jj] = f32x4{0.f, 0.f, 0.f, 0.f};
    const int jcol = t & 127;
    const int hf   = t >> 7;
    const int gcol = nt * 128 + jcol;
    const float* w2e = W2 + (size_t)e * INTER * HID;
    for (int k0 = 0; k0 < INTER; k0 += BK) {
#pragma unroll
        for (int it = 0; it < 4; ++it) {
            int lin = it * 256 + t;
            int r   = lin >> 3;
            int kq  = (lin & 7) << 3;
            uint4 v = *reinterpret_cast<const uint4*>(
                inter + (size_t)(rowbase + r) * INTER + k0 + kq);
            *reinterpret_cast<uint4*>(&As[r][kq]) = v;
        }
#pragma unroll
        for (int it = 0; it < 8; ++it) {
            int kq = hf * 4 + it * 8;
            const float* p = w2e + (size_t)(k0 + kq) * HID + gcol;
            float v0 = p[0], v1 = p[HID], v2 = p[2 * HID], v3 = p[3 * HID];
            ushort4 o;
            o.x = f2bf(v0); o.y = f2bf(v1); o.z = f2bf(v2); o.w = f2bf(v3);
            *reinterpret_cast<ushort4*>(&Bs[jcol][kq]) = o;
        }
        __syncthreads();
#pragma unroll
        for (int kk = 0; kk < 2; ++kk) {
            const int kb = kk * 32 + ((lane >> 4) << 3);
            bf16x8 a0 = *reinterpret_cast<const bf16x8*>(&As[w * 32 + (lane & 15)][kb]);
            bf16x8 a1 = *reinterpret_cast<const bf16x8*>(&As[w * 32 + 16 + (lane & 15)][kb]);
#pragma unroll
            for (int nf = 0; nf < 8; ++nf) {
                bf16x8 b = *reinterpret_cast<const bf16x8*>(&Bs[nf * 16 + (lane & 15)][kb]);
                acc[0][nf] = MFMA_BF16(a0, b, acc[0][nf]);
                acc[1][nf] = MFMA_BF16(a1, b, acc[1][nf]);
            }
        }
        __syncthreads();
    }
    const int rl0 = w * 32 + ((lane >> 4) << 2);
    const int cl  = lane & 15;
#pragma unroll
    for (int mf = 0; mf < 2; ++mf)
#pragma unroll
        for (int nf = 0; nf < 8; ++nf) {
            f32x4 v = acc[mf][nf];
#pragma unroll
            for (int r = 0; r < 4; ++r) {
                int row = rowbase + rl0 + mf * 16 + r;
                int col = nt * 128 + nf * 16 + cl;
                out[(size_t)row * HID + col] = v[r];
            }
        }
}

// ---------------- launch ----------------

extern "C" void kernel_launch(void* const* d_in, const int* in_sizes, int n_in,
                              void* d_out, int out_size, void* d_ws, size_t ws_size,
                              hipStream_t stream) {
    const float* X  = (const float*)d_in[0];
    const float* W1 = (const float*)d_in[1];
    const float* W2 = (const float*)d_in[2];
    float* out = (float*)d_out;

    const size_t XB_B  = (size_t)EXPERTS * TOK * HID * 2;
    const size_t W1T_B = (size_t)EXPERTS * I2 * HID * 2;
    const size_t W2T_B = (size_t)EXPERTS * HID * INTER * 2;
    const size_t INT_B = (size_t)EXPERTS * TOK * INTER * 2;
    const size_t need  = XB_B + W1T_B + W2T_B + INT_B;

    if (ws_size >= need) {
        unsigned short* Xb    = (unsigned short*)d_ws;
        unsigned short* w1t   = (unsigned short*)((char*)d_ws + XB_B);
        unsigned short* w2t   = (unsigned short*)((char*)d_ws + XB_B + W1T_B);
        unsigned short* inter = (unsigned short*)((char*)d_ws + XB_B + W1T_B + W2T_B);

        hipFuncSetAttribute((const void*)k_fc1_r3,
            hipFuncAttributeMaxDynamicSharedMemorySize, 98304);
        hipFuncSetAttribute((const void*)k_fc2_r3,
            hipFuncAttributeMaxDynamicSharedMemorySize, 98304);

        dim3 b256(256), b1024(1024);
        k_cvt_x <<<(EXPERTS * TOK * HID) / (256 * 8), b256, 0, stream>>>(X, Xb);
        k_cvt_w1<<<EXPERTS * (I2 / 64) * (HID / 64),   b256, 0, stream>>>(W1, w1t);
        k_cvt_w2<<<EXPERTS * (HID / 64) * (INTER / 64), b256, 0, stream>>>(W2, w2t);
        k_fc1_r3<<<EXPERTS * 4 * (I2 / 256),  b1024, 98304, stream>>>(Xb, w1t, inter);
        k_fc2_r3<<<EXPERTS * 4 * (HID / 256), b1024, 98304, stream>>>(inter, w2t, out);
    } else {
        unsigned short* inter = (unsigned short*)d_ws;
        dim3 b256(256);
        k_fc1_glu_fb<<<EXPERTS * (TOK / BM) * (INTER / 64), b256, 0, stream>>>(X, W1, inter);
        k_fc2_fb    <<<EXPERTS * (TOK / BM) * (HID / 128),  b256, 0, stream>>>(inter, W2, out);
    }
}